// Round 1
// baseline (973.695 us; speedup 1.0000x reference)
//
#include <hip/hip_runtime.h>

typedef unsigned short u16;
typedef float f32x4 __attribute__((ext_vector_type(4)));
typedef __bf16 bf16x8 __attribute__((ext_vector_type(8)));

#define DEV static __device__ __forceinline__

DEV u16 f2bf(float f) {
  union { float f; unsigned u; } c; c.f = f;
  unsigned u = c.u;
  u += 0x7fffu + ((u >> 16) & 1u);   // RNE; inputs are normal floats
  return (u16)(u >> 16);
}
DEV float bf2f(u16 h) {
  union { float f; unsigned u; } c; c.u = ((unsigned)h) << 16;
  return c.f;
}
DEV f32x4 MFMA(bf16x8 a, bf16x8 b, f32x4 c) {
  return __builtin_amdgcn_mfma_f32_16x16x32_bf16(a, b, c, 0, 0, 0);
}

// ---------------- constants ----------------
// B=2 L=2048 DM=2048 H=16 KV=4 GROUP=4 DK=128 DV=512
// qkv row layout: [0,2048) q (16x128) | [2048,2560) k (4x128) | [2560,4608) v (4x512)

// ---------------- RoPE tables ----------------
__global__ void rope_tables(float* __restrict__ sinT, float* __restrict__ cosT) {
  int idx = blockIdx.x * 256 + threadIdx.x;     // 2048*64
  int l = idx >> 6, i = idx & 63;
  float inv = __expf(-((float)(2 * i) / 128.0f) * 9.210340371976184f); // 10000^(-2i/128)
  float ang = (float)l * inv;
  sinT[idx] = sinf(ang);
  cosT[idx] = cosf(ang);
}

// ---------------- cast x -> bf16 ----------------
__global__ void cast_f32_bf16(const float* __restrict__ in, u16* __restrict__ out) {
  int i = (blockIdx.x * 256 + threadIdx.x) * 4;
  float4 v = *(const float4*)(in + i);
  ushort4 o;
  o.x = f2bf(v.x); o.y = f2bf(v.y); o.z = f2bf(v.z); o.w = f2bf(v.w);
  *(ushort4*)(out + i) = o;
}

// ---------------- transpose + cast: fp32 [R][C] -> bf16 [C][R] ----------------
__global__ void transpose_cast(const float* __restrict__ in, u16* __restrict__ out,
                               int R, int C) {
  __shared__ u16 tile[32][33];
  int c0 = blockIdx.x * 32, r0 = blockIdx.y * 32;
  int tx = threadIdx.x, ty = threadIdx.y;   // 32 x 8
  for (int i = 0; i < 32; i += 8)
    tile[ty + i][tx] = f2bf(in[(size_t)(r0 + ty + i) * C + c0 + tx]);
  __syncthreads();
  for (int i = 0; i < 32; i += 8)
    out[(size_t)(c0 + ty + i) * R + r0 + tx] = tile[tx][ty + i];
}

// ---------------- GEMM: C[M][N] = A[M][K](bf16) @ Bt[N][K](bf16)^T ----------------
// 128x128 tile, BK=32, 256 thr (2x2 waves of 64x64), reg-staged LDS w/ XOR swizzle.
template <int WRITE_F32>
__global__ __launch_bounds__(256) void gemm_bt(
    const u16* __restrict__ A, const u16* __restrict__ Bt,
    float* __restrict__ Cf, u16* __restrict__ Cb,
    const float* __restrict__ bias, int N, int K) {
  __shared__ __align__(16) u16 lA[128 * 32];
  __shared__ __align__(16) u16 lB[128 * 32];
  const int bn = blockIdx.x, bm = blockIdx.y;
  const int t = threadIdx.x, w = t >> 6, l = t & 63;
  const int wr = w >> 1, wc = w & 1;
  const int lr = l & 15, lg = l >> 4;

  f32x4 zero = {0.f, 0.f, 0.f, 0.f};
  f32x4 acc[4][4];
#pragma unroll
  for (int m = 0; m < 4; ++m)
#pragma unroll
    for (int n = 0; n < 4; ++n) acc[m][n] = zero;

  const int srow = t >> 2, sslot = t & 3;    // tile [128][32]: row=64B, 4x16B slots
  const size_t aBase = (size_t)(bm * 128) * K;
  const size_t bBase = (size_t)(bn * 128) * K;

  for (int k0 = 0; k0 < K; k0 += 32) {
    if (k0) __syncthreads();
#pragma unroll
    for (int i = 0; i < 2; ++i) {
      int row = srow + i * 64;
      int sw = (sslot ^ (row & 3)) & 3;
      bf16x8 va = *(const bf16x8*)(A + aBase + (size_t)row * K + k0 + sslot * 8);
      *(bf16x8*)((char*)lA + row * 64 + sw * 16) = va;
      bf16x8 vb = *(const bf16x8*)(Bt + bBase + (size_t)row * K + k0 + sslot * 8);
      *(bf16x8*)((char*)lB + row * 64 + sw * 16) = vb;
    }
    __syncthreads();

    bf16x8 af[4], bf[4];
#pragma unroll
    for (int m = 0; m < 4; ++m) {
      int row = wr * 64 + m * 16 + lr;
      int sw = (lg ^ (row & 3)) & 3;
      af[m] = *(const bf16x8*)((char*)lA + row * 64 + sw * 16);
    }
#pragma unroll
    for (int n = 0; n < 4; ++n) {
      int row = wc * 64 + n * 16 + lr;
      int sw = (lg ^ (row & 3)) & 3;
      bf[n] = *(const bf16x8*)((char*)lB + row * 64 + sw * 16);
    }
#pragma unroll
    for (int m = 0; m < 4; ++m)
#pragma unroll
      for (int n = 0; n < 4; ++n)
        acc[m][n] = MFMA(af[m], bf[n], acc[m][n]);
  }

#pragma unroll
  for (int m = 0; m < 4; ++m) {
#pragma unroll
    for (int n = 0; n < 4; ++n) {
      int col = bn * 128 + wc * 64 + n * 16 + lr;
      float bv = WRITE_F32 ? bias[col] : 0.f;
#pragma unroll
      for (int j = 0; j < 4; ++j) {
        size_t rowg = (size_t)(bm * 128 + wr * 64 + m * 16 + lg * 4 + j);
        float v = acc[m][n][j];
        if (WRITE_F32) Cf[rowg * N + col] = v + bv;
        else           Cb[rowg * N + col] = f2bf(v);
      }
    }
  }
}

// ---------------- RoPE in-place on bf16 qkv (q: 16 heads, k: 4 heads) ----------------
__global__ void rope_kernel(u16* __restrict__ qkv, const float* __restrict__ sinT,
                            const float* __restrict__ cosT) {
  int idx = blockIdx.x * 256 + threadIdx.x;   // 4096 rows * 20 heads * 64
  int d = idx & 63;
  int rh = idx >> 6;
  int head = rh % 20;
  int row = rh / 20;
  int lpos = row & 2047;
  int col = head < 16 ? head * 128 : 2048 + (head - 16) * 128;
  u16* p = qkv + (size_t)row * 4608 + col;
  float x1 = bf2f(p[d]), x2 = bf2f(p[d + 64]);
  float c = cosT[lpos * 64 + d], s = sinT[lpos * 64 + d];
  p[d]      = f2bf(x1 * c - x2 * s);
  p[d + 64] = f2bf(x2 * c + x1 * s);
}

// ---------------- V^T builder: vT[(b*4+kv)*512 + e][l] = qkv[b*2048+l][2560+kv*512+e] ----
__global__ void vt_kernel(const u16* __restrict__ qkv, u16* __restrict__ vT) {
  __shared__ u16 tile[32][33];
  int bkv = blockIdx.z;
  int b = bkv >> 2, kv = bkv & 3;
  int e0 = blockIdx.x * 32, l0 = blockIdx.y * 32;
  const u16* src = qkv + (size_t)(b * 2048) * 4608 + 2560 + kv * 512;
  int tx = threadIdx.x, ty = threadIdx.y;   // 32 x 8
  for (int i = 0; i < 32; i += 8)
    tile[ty + i][tx] = src[(size_t)(l0 + ty + i) * 4608 + e0 + tx];
  __syncthreads();
  u16* dst = vT + (size_t)(bkv * 512) * 2048;
  for (int i = 0; i < 32; i += 8)
    dst[(size_t)(e0 + ty + i) * 2048 + l0 + tx] = tile[tx][ty + i];
}

// ---------------- flash attention ----------------
// grid (L/64, H, B), 256 thr. wave w owns q-rows [qt*64+w*16, +16). KVBLK=32.
__global__ __launch_bounds__(256) void attn_kernel(
    const u16* __restrict__ qkv, const u16* __restrict__ vT,
    u16* __restrict__ ctxb) {
  const int qt = blockIdx.x, h = blockIdx.y, b = blockIdx.z;
  const int kv = h >> 2;
  const int t = threadIdx.x, w = t >> 6, l = t & 63;
  const int lr = l & 15, lg = l >> 4;

  __shared__ __align__(16) u16 lK[32 * 128];   // [kv][d] swizzled, 8KB
  __shared__ __align__(16) u16 lV[512 * 32];   // [e][kv] swizzled, 32KB
  __shared__ __align__(16) u16 lP[4 * 16 * 32]; // per-wave P, 4KB

  const float scale = 0.08838834764831845f;    // 1/sqrt(128)
  f32x4 zero = {0.f, 0.f, 0.f, 0.f};

  // Q fragments (A-operand): rows = qt*64 + w*16 + lr
  const size_t qrow = (size_t)(b * 2048 + qt * 64 + w * 16 + lr);
  bf16x8 qf[4];
#pragma unroll
  for (int dc = 0; dc < 4; ++dc)
    qf[dc] = *(const bf16x8*)(qkv + qrow * 4608 + h * 128 + dc * 32 + lg * 8);

  f32x4 acc[32];
#pragma unroll
  for (int e = 0; e < 32; ++e) acc[e] = zero;
  float m_r[4] = {-1e30f, -1e30f, -1e30f, -1e30f};
  float l_r[4] = {0.f, 0.f, 0.f, 0.f};

  const size_t kbase = (size_t)(b * 2048) * 4608 + 2048 + kv * 128;
  const size_t vbase = (size_t)((b * 4 + kv) * 512) * 2048;

  for (int kv0 = 0; kv0 < 2048; kv0 += 32) {
    if (kv0) __syncthreads();
    // stage K tile 32x128 (512 x 16B chunks)
#pragma unroll
    for (int i = 0; i < 2; ++i) {
      int c = i * 256 + t;
      int row = c >> 4, s = c & 15;
      int sw = (s & 8) | ((s ^ (row & 7)) & 7);
      bf16x8 v = *(const bf16x8*)(qkv + kbase + (size_t)(kv0 + row) * 4608 + s * 8);
      *(bf16x8*)((char*)lK + row * 256 + sw * 16) = v;
    }
    // stage V^T tile 512x32 (2048 x 16B chunks)
#pragma unroll
    for (int i = 0; i < 8; ++i) {
      int c = i * 256 + t;
      int e = c >> 2, s = c & 3;
      int sw = (s ^ (e & 3)) & 3;
      bf16x8 v = *(const bf16x8*)(vT + vbase + (size_t)e * 2048 + kv0 + s * 8);
      *(bf16x8*)((char*)lV + e * 64 + sw * 16) = v;
    }
    __syncthreads();

    // S = Q K^T : two 16x16 col-tiles
    f32x4 s0 = zero, s1 = zero;
#pragma unroll
    for (int dc = 0; dc < 4; ++dc) {
      int slot = dc * 4 + lg;
      int sw0 = (slot & 8) | ((slot ^ (lr & 7)) & 7);
      bf16x8 kf0 = *(const bf16x8*)((char*)lK + lr * 256 + sw0 * 16);
      s0 = MFMA(qf[dc], kf0, s0);
      int kr1 = 16 + lr;
      int sw1 = (slot & 8) | ((slot ^ (kr1 & 7)) & 7);
      bf16x8 kf1 = *(const bf16x8*)((char*)lK + kr1 * 256 + sw1 * 16);
      s1 = MFMA(qf[dc], kf1, s1);
    }

    // online softmax (rows = lg*4+j), defer-max THR=8
    float rmax[4];
#pragma unroll
    for (int j = 0; j < 4; ++j) {
      s0[j] *= scale; s1[j] *= scale;
      float r = fmaxf(s0[j], s1[j]);
      r = fmaxf(r, __shfl_xor(r, 1));
      r = fmaxf(r, __shfl_xor(r, 2));
      r = fmaxf(r, __shfl_xor(r, 4));
      r = fmaxf(r, __shfl_xor(r, 8));
      rmax[j] = r;
    }
    bool need = (rmax[0] > m_r[0] + 8.f) || (rmax[1] > m_r[1] + 8.f) ||
                (rmax[2] > m_r[2] + 8.f) || (rmax[3] > m_r[3] + 8.f);
    if (__any(need)) {
#pragma unroll
      for (int j = 0; j < 4; ++j) {
        float mn = fmaxf(m_r[j], rmax[j]);
        float al = __expf(m_r[j] - mn);
        m_r[j] = mn;
        l_r[j] *= al;
#pragma unroll
        for (int e = 0; e < 32; ++e) acc[e][j] *= al;
      }
    }
    float p0[4], p1[4];
#pragma unroll
    for (int j = 0; j < 4; ++j) {
      p0[j] = __expf(s0[j] - m_r[j]);
      p1[j] = __expf(s1[j] - m_r[j]);
      float ps = p0[j] + p1[j];
      ps += __shfl_xor(ps, 1);
      ps += __shfl_xor(ps, 2);
      ps += __shfl_xor(ps, 4);
      ps += __shfl_xor(ps, 8);
      l_r[j] += ps;
    }
    // P -> LDS (per-wave) then read back as A-fragment
    u16* lPw = lP + w * 512;
#pragma unroll
    for (int j = 0; j < 4; ++j) {
      int row = lg * 4 + j;
      lPw[row * 32 + lr]      = f2bf(p0[j]);
      lPw[row * 32 + 16 + lr] = f2bf(p1[j]);
    }
    bf16x8 pf = *(const bf16x8*)(lPw + lr * 32 + lg * 8);
    // PV: ctx[16 x 512] += P[16x32] @ V[32x512]
#pragma unroll
    for (int e = 0; e < 32; ++e) {
      int er = e * 16 + lr;
      int sw = (lg ^ (er & 3)) & 3;
      bf16x8 vf = *(const bf16x8*)((char*)lV + er * 64 + sw * 16);
      acc[e] = MFMA(pf, vf, acc[e]);
    }
  }

  float inv[4];
#pragma unroll
  for (int j = 0; j < 4; ++j) inv[j] = 1.0f / l_r[j];
  const size_t orow0 = (size_t)(b * 2048 + qt * 64 + w * 16 + lg * 4);
#pragma unroll
  for (int e = 0; e < 32; ++e)
#pragma unroll
    for (int j = 0; j < 4; ++j)
      ctxb[(orow0 + j) * 8192 + h * 512 + e * 16 + lr] = f2bf(acc[e][j] * inv[j]);
}

// ---------------- launch ----------------
extern "C" void kernel_launch(void* const* d_in, const int* in_sizes, int n_in,
                              void* d_out, int out_size, void* d_ws, size_t ws_size,
                              hipStream_t stream) {
  const float* x      = (const float*)d_in[0];
  const float* W_attn = (const float*)d_in[1];
  const float* W_out  = (const float*)d_in[2];
  const float* b_out  = (const float*)d_in[3];
  float* out = (float*)d_out;
  char* ws = (char*)d_ws;

  if (ws_size < 158334976u) return;  // need ~151MB scratch

  float* sinT = (float*)(ws + 0);
  float* cosT = (float*)(ws + 524288);
  u16* xb   = (u16*)(ws + 1048576);    // 16MB   (dead after GEMM1)
  u16* WbT  = (u16*)(ws + 17825792);   // 18MB   (dead after GEMM1)
  u16* qkvb = (u16*)(ws + 36700160);   // 36MB
  u16* vT   = (u16*)(ws + 74448896);   // 16MB
  u16* ctxb = (u16*)(ws + 91226112);   // 64MB
  u16* WobT = (u16*)(ws + 1048576);    // 32MB, reuses xb+WbT region post-GEMM1

  rope_tables<<<512, 256, 0, stream>>>(sinT, cosT);
  cast_f32_bf16<<<8192, 256, 0, stream>>>(x, xb);
  transpose_cast<<<dim3(144, 64), dim3(32, 8), 0, stream>>>(W_attn, WbT, 2048, 4608);
  gemm_bt<0><<<dim3(36, 32), 256, 0, stream>>>(xb, WbT, nullptr, qkvb, nullptr, 4608, 2048);
  rope_kernel<<<20480, 256, 0, stream>>>(qkvb, sinT, cosT);
  vt_kernel<<<dim3(16, 64, 8), dim3(32, 8), 0, stream>>>(qkvb, vT);
  attn_kernel<<<dim3(32, 16, 2), 256, 0, stream>>>(qkvb, vT, ctxb);
  transpose_cast<<<dim3(64, 256), dim3(32, 8), 0, stream>>>(W_out, WobT, 8192, 2048);
  gemm_bt<1><<<dim3(16, 32), 256, 0, stream>>>(ctxb, WobT, out, nullptr, b_out, 2048, 8192);
}

// Round 2
// 811.576 us; speedup vs baseline: 1.1998x; 1.1998x over previous
//
#include <hip/hip_runtime.h>

typedef unsigned short u16;
typedef float f32x4 __attribute__((ext_vector_type(4)));
typedef __bf16 bf16x8 __attribute__((ext_vector_type(8)));

#define DEV static __device__ __forceinline__

DEV u16 f2bf(float f) {
  union { float f; unsigned u; } c; c.f = f;
  unsigned u = c.u;
  u += 0x7fffu + ((u >> 16) & 1u);   // RNE; inputs are normal floats
  return (u16)(u >> 16);
}
DEV float bf2f(u16 h) {
  union { float f; unsigned u; } c; c.u = ((unsigned)h) << 16;
  return c.f;
}
DEV f32x4 MFMA(bf16x8 a, bf16x8 b, f32x4 c) {
  return __builtin_amdgcn_mfma_f32_16x16x32_bf16(a, b, c, 0, 0, 0);
}

// ---------------- constants ----------------
// B=2 L=2048 DM=2048 H=16 KV=4 GROUP=4 DK=128 DV=512
// qkv row layout: [0,2048) q (16x128) | [2048,2560) k (4x128) | [2560,4608) v (4x512)

// ---------------- RoPE tables ----------------
__global__ void rope_tables(float* __restrict__ sinT, float* __restrict__ cosT) {
  int idx = blockIdx.x * 256 + threadIdx.x;     // 2048*64
  int l = idx >> 6, i = idx & 63;
  float inv = __expf(-((float)(2 * i) / 128.0f) * 9.210340371976184f); // 10000^(-2i/128)
  float ang = (float)l * inv;
  sinT[idx] = sinf(ang);
  cosT[idx] = cosf(ang);
}

// ---------------- cast x -> bf16 ----------------
__global__ void cast_f32_bf16(const float* __restrict__ in, u16* __restrict__ out) {
  int i = (blockIdx.x * 256 + threadIdx.x) * 4;
  float4 v = *(const float4*)(in + i);
  ushort4 o;
  o.x = f2bf(v.x); o.y = f2bf(v.y); o.z = f2bf(v.z); o.w = f2bf(v.w);
  *(ushort4*)(out + i) = o;
}

// ---------------- transpose + cast: fp32 [R][C] -> bf16 [C][R] ----------------
__global__ void transpose_cast(const float* __restrict__ in, u16* __restrict__ out,
                               int R, int C) {
  __shared__ u16 tile[32][33];
  int c0 = blockIdx.x * 32, r0 = blockIdx.y * 32;
  int tx = threadIdx.x, ty = threadIdx.y;   // 32 x 8
  for (int i = 0; i < 32; i += 8)
    tile[ty + i][tx] = f2bf(in[(size_t)(r0 + ty + i) * C + c0 + tx]);
  __syncthreads();
  for (int i = 0; i < 32; i += 8)
    out[(size_t)(c0 + ty + i) * R + r0 + tx] = tile[tx][ty + i];
}

// ---------------- GEMM: C[M][N] = A[M][K](bf16) @ Bt[N][K](bf16)^T ----------------
template <int WRITE_F32>
__global__ __launch_bounds__(256) void gemm_bt(
    const u16* __restrict__ A, const u16* __restrict__ Bt,
    float* __restrict__ Cf, u16* __restrict__ Cb,
    const float* __restrict__ bias, int N, int K) {
  __shared__ __align__(16) u16 lA[128 * 32];
  __shared__ __align__(16) u16 lB[128 * 32];
  const int bn = blockIdx.x, bm = blockIdx.y;
  const int t = threadIdx.x, w = t >> 6, l = t & 63;
  const int wr = w >> 1, wc = w & 1;
  const int lr = l & 15, lg = l >> 4;

  f32x4 zero = {0.f, 0.f, 0.f, 0.f};
  f32x4 acc[4][4];
#pragma unroll
  for (int m = 0; m < 4; ++m)
#pragma unroll
    for (int n = 0; n < 4; ++n) acc[m][n] = zero;

  const int srow = t >> 2, sslot = t & 3;    // tile [128][32]: row=64B, 4x16B slots
  const size_t aBase = (size_t)(bm * 128) * K;
  const size_t bBase = (size_t)(bn * 128) * K;

  for (int k0 = 0; k0 < K; k0 += 32) {
    if (k0) __syncthreads();
#pragma unroll
    for (int i = 0; i < 2; ++i) {
      int row = srow + i * 64;
      int sw = (sslot ^ (row & 3)) & 3;
      bf16x8 va = *(const bf16x8*)(A + aBase + (size_t)row * K + k0 + sslot * 8);
      *(bf16x8*)((char*)lA + row * 64 + sw * 16) = va;
      bf16x8 vb = *(const bf16x8*)(Bt + bBase + (size_t)row * K + k0 + sslot * 8);
      *(bf16x8*)((char*)lB + row * 64 + sw * 16) = vb;
    }
    __syncthreads();

    bf16x8 af[4], bf[4];
#pragma unroll
    for (int m = 0; m < 4; ++m) {
      int row = wr * 64 + m * 16 + lr;
      int sw = (lg ^ (row & 3)) & 3;
      af[m] = *(const bf16x8*)((char*)lA + row * 64 + sw * 16);
    }
#pragma unroll
    for (int n = 0; n < 4; ++n) {
      int row = wc * 64 + n * 16 + lr;
      int sw = (lg ^ (row & 3)) & 3;
      bf[n] = *(const bf16x8*)((char*)lB + row * 64 + sw * 16);
    }
#pragma unroll
    for (int m = 0; m < 4; ++m)
#pragma unroll
      for (int n = 0; n < 4; ++n)
        acc[m][n] = MFMA(af[m], bf[n], acc[m][n]);
  }

#pragma unroll
  for (int m = 0; m < 4; ++m) {
#pragma unroll
    for (int n = 0; n < 4; ++n) {
      int col = bn * 128 + wc * 64 + n * 16 + lr;
      float bv = WRITE_F32 ? bias[col] : 0.f;
#pragma unroll
      for (int j = 0; j < 4; ++j) {
        size_t rowg = (size_t)(bm * 128 + wr * 64 + m * 16 + lg * 4 + j);
        float v = acc[m][n][j];
        if (WRITE_F32) Cf[rowg * N + col] = v + bv;
        else           Cb[rowg * N + col] = f2bf(v);
      }
    }
  }
}

// ---------------- RoPE in-place on bf16 qkv (q: 16 heads, k: 4 heads) ----------------
__global__ void rope_kernel(u16* __restrict__ qkv, const float* __restrict__ sinT,
                            const float* __restrict__ cosT) {
  int idx = blockIdx.x * 256 + threadIdx.x;   // 4096 rows * 20 heads * 64
  int d = idx & 63;
  int rh = idx >> 6;
  int head = rh % 20;
  int row = rh / 20;
  int lpos = row & 2047;
  int col = head < 16 ? head * 128 : 2048 + (head - 16) * 128;
  u16* p = qkv + (size_t)row * 4608 + col;
  float x1 = bf2f(p[d]), x2 = bf2f(p[d + 64]);
  float c = cosT[lpos * 64 + d], s = sinT[lpos * 64 + d];
  p[d]      = f2bf(x1 * c - x2 * s);
  p[d + 64] = f2bf(x2 * c + x1 * s);
}

// ---------------- V^T builder: vT[(b*4+kv)*512 + e][l] = qkv[b*2048+l][2560+kv*512+e] ----
__global__ void vt_kernel(const u16* __restrict__ qkv, u16* __restrict__ vT) {
  __shared__ u16 tile[32][33];
  int bkv = blockIdx.z;
  int b = bkv >> 2, kv = bkv & 3;
  int e0 = blockIdx.x * 32, l0 = blockIdx.y * 32;
  const u16* src = qkv + (size_t)(b * 2048) * 4608 + 2560 + kv * 512;
  int tx = threadIdx.x, ty = threadIdx.y;   // 32 x 8
  for (int i = 0; i < 32; i += 8)
    tile[ty + i][tx] = src[(size_t)(l0 + ty + i) * 4608 + e0 + tx];
  __syncthreads();
  u16* dst = vT + (size_t)(bkv * 512) * 2048;
  for (int i = 0; i < 32; i += 8)
    dst[(size_t)(e0 + ty + i) * 2048 + l0 + tx] = tile[tx][ty + i];
}

// ---------------- flash attention (rewritten) ----------------
// 512 linear blocks: pg = wg&7 -> (kvg, b) panel (XCD-grouped), qt = wg>>3.
// 512 thr = 8 waves: wave w -> head h4=w>>1, e-half eh=w&1.
// Wave: 32 q-rows (m=0,1) x 256 e-cols (16 e-tiles), KVBLK=32, reg-prefetch dbuf.
// LDS: lK [32][128] 16-slot swizzle; lV packed [256][2x32] 8-slot swizzle;
//      lP per-wave packed [16][2x32] 8-slot swizzle. Total 56KB.
__global__ __launch_bounds__(512, 2) void attn_kernel(
    const u16* __restrict__ qkv, const u16* __restrict__ vT,
    u16* __restrict__ ctxb) {
  const int wg = blockIdx.x;
  const int pg = wg & 7, qt = wg >> 3;
  const int kvg = pg & 3, b = pg >> 2;
  const int t = threadIdx.x, w = t >> 6, l = t & 63;
  const int lr = l & 15, lg = l >> 4;
  const int h4 = w >> 1, eh = w & 1;
  const int h = kvg * 4 + h4;

  __shared__ __align__(16) u16 lK[32 * 128];   // 8KB
  __shared__ __align__(16) u16 lV[512 * 32];   // 32KB (packed rows of 128B)
  __shared__ __align__(16) u16 lP[8 * 1024];   // 16KB (2KB/wave)

  const float scale = 0.08838834764831845f;    // 1/sqrt(128)
  f32x4 zero = {0.f, 0.f, 0.f, 0.f};

  // Q fragments: qf[m][dc], rows qt*32 + m*16 + lr
  bf16x8 qf[2][4];
  const size_t qbase = (size_t)(b * 2048 + qt * 32);
#pragma unroll
  for (int m = 0; m < 2; ++m)
#pragma unroll
    for (int dc = 0; dc < 4; ++dc)
      qf[m][dc] = *(const bf16x8*)(qkv + (qbase + m * 16 + lr) * 4608 + h * 128 + dc * 32 + lg * 8);

  f32x4 acc[2][16];
#pragma unroll
  for (int m = 0; m < 2; ++m)
#pragma unroll
    for (int e = 0; e < 16; ++e) acc[m][e] = zero;
  float m_r[2][4], l_r[2][4];
#pragma unroll
  for (int m = 0; m < 2; ++m)
#pragma unroll
    for (int j = 0; j < 4; ++j) { m_r[m][j] = -1e30f; l_r[m][j] = 0.f; }

  const size_t kbase = (size_t)(b * 2048) * 4608 + 2048 + kvg * 128;
  const size_t vbase = (size_t)((b * 4 + kvg) * 512) * 2048;

  // staging addresses (lane-constant)
  const u16* vsrc = vT + vbase + (size_t)(t >> 2) * 2048 + (t & 3) * 8;
  const u16* ksrc = qkv + kbase + (size_t)(t >> 4) * 4608 + (t & 15) * 8;
  char* vdst;
  { int slot = ((t >> 2) & 1) * 4 + (t & 3);
    int sw = slot ^ ((t >> 3) & 7);
    vdst = (char*)lV + (t >> 3) * 128 + sw * 16; }
  char* kdst;
  { int s = t & 15, r7 = (t >> 4) & 7;
    int sw = (s & 8) | ((s ^ r7) & 7);
    kdst = (char*)lK + (t >> 4) * 256 + sw * 16; }

  // fragment-read offsets (lane-constant parts)
  const int psw16 = ((((lr & 1) * 4) + lg) ^ ((lr >> 1) & 7)) * 16;  // shared by vf/pf
  const int vfbase = eh * 16384 + (lr >> 1) * 128 + psw16;
  char* lPw = (char*)lP + w * 2048;

  // prologue: prefetch tile kv0=0 into regs
  bf16x8 vreg[4], kreg;
#pragma unroll
  for (int i = 0; i < 4; ++i) vreg[i] = *(const bf16x8*)(vsrc + (size_t)i * 262144);
  kreg = *(const bf16x8*)(ksrc);

  for (int kv0 = 0; kv0 < 2048; kv0 += 32) {
    __syncthreads();                       // prior compute done reading LDS
#pragma unroll
    for (int i = 0; i < 4; ++i) *(bf16x8*)(vdst + i * 8192) = vreg[i];
    *(bf16x8*)(kdst) = kreg;
    if (kv0 + 32 < 2048) {                 // prefetch next tile (hides under compute)
#pragma unroll
      for (int i = 0; i < 4; ++i)
        vreg[i] = *(const bf16x8*)(vsrc + (kv0 + 32) + (size_t)i * 262144);
      kreg = *(const bf16x8*)(ksrc + (size_t)(kv0 + 32) * 4608);
    }
    __syncthreads();                       // tile staged

    // ---- QK^T: S[2m][2kt] tiles, kf reused across m ----
    f32x4 sA[2][2];
    sA[0][0] = zero; sA[0][1] = zero; sA[1][0] = zero; sA[1][1] = zero;
#pragma unroll
    for (int dc = 0; dc < 4; ++dc) {
      int slot = dc * 4 + lg;
      int sw = (slot & 8) | ((slot ^ (lr & 7)) & 7);
#pragma unroll
      for (int kt = 0; kt < 2; ++kt) {
        bf16x8 kf = *(const bf16x8*)((char*)lK + (kt * 16 + lr) * 256 + sw * 16);
        sA[0][kt] = MFMA(qf[0][dc], kf, sA[0][kt]);
        sA[1][kt] = MFMA(qf[1][dc], kf, sA[1][kt]);
      }
    }

    // ---- online softmax (rows m*16 + lg*4 + j), defer-max THR=8 ----
    float rmax[2][4];
#pragma unroll
    for (int m = 0; m < 2; ++m)
#pragma unroll
      for (int j = 0; j < 4; ++j) {
        sA[m][0][j] *= scale; sA[m][1][j] *= scale;
        float r = fmaxf(sA[m][0][j], sA[m][1][j]);
        r = fmaxf(r, __shfl_xor(r, 1));
        r = fmaxf(r, __shfl_xor(r, 2));
        r = fmaxf(r, __shfl_xor(r, 4));
        r = fmaxf(r, __shfl_xor(r, 8));
        rmax[m][j] = r;
      }
    bool need = false;
#pragma unroll
    for (int m = 0; m < 2; ++m)
#pragma unroll
      for (int j = 0; j < 4; ++j) need = need || (rmax[m][j] > m_r[m][j] + 8.f);
    if (__any(need)) {
#pragma unroll
      for (int m = 0; m < 2; ++m)
#pragma unroll
        for (int j = 0; j < 4; ++j) {
          float mn = fmaxf(m_r[m][j], rmax[m][j]);
          float al = __expf(m_r[m][j] - mn);
          m_r[m][j] = mn;
          l_r[m][j] *= al;
#pragma unroll
          for (int e = 0; e < 16; ++e) acc[m][e][j] *= al;
        }
    }
#pragma unroll
    for (int m = 0; m < 2; ++m)
#pragma unroll
      for (int j = 0; j < 4; ++j) {
        sA[m][0][j] = __expf(sA[m][0][j] - m_r[m][j]);
        sA[m][1][j] = __expf(sA[m][1][j] - m_r[m][j]);
        float ps = sA[m][0][j] + sA[m][1][j];
        ps += __shfl_xor(ps, 1);
        ps += __shfl_xor(ps, 2);
        ps += __shfl_xor(ps, 4);
        ps += __shfl_xor(ps, 8);
        l_r[m][j] += ps;
      }

    // ---- P -> per-wave LDS (packed+swizzled), read back as A-frags ----
#pragma unroll
    for (int m = 0; m < 2; ++m)
#pragma unroll
      for (int j = 0; j < 4; ++j) {
        int rr = lg * 2 + (j >> 1);            // (row>>1) within m-half
#pragma unroll
        for (int kt = 0; kt < 2; ++kt) {
          int slot = (j & 1) * 4 + kt * 2 + (lr >> 3);
          int addr = (m * 8 + rr) * 128 + ((slot ^ (rr & 7)) & 7) * 16 + (lr & 7) * 2;
          *(u16*)(lPw + addr) = f2bf(sA[m][kt][j]);
        }
      }
    bf16x8 pf[2];
#pragma unroll
    for (int m = 0; m < 2; ++m)
      pf[m] = *(const bf16x8*)(lPw + (m * 8 + (lr >> 1)) * 128 + psw16);

    // ---- PV: vf reused across m ----
#pragma unroll
    for (int e = 0; e < 16; ++e) {
      bf16x8 vf = *(const bf16x8*)((char*)lV + vfbase + e * 1024);
      acc[0][e] = MFMA(pf[0], vf, acc[0][e]);
      acc[1][e] = MFMA(pf[1], vf, acc[1][e]);
    }
  }

  // ---- epilogue ----
#pragma unroll
  for (int m = 0; m < 2; ++m) {
    float inv[4];
#pragma unroll
    for (int j = 0; j < 4; ++j) inv[j] = 1.0f / l_r[m][j];
    const size_t orow0 = qbase + m * 16 + lg * 4;
#pragma unroll
    for (int e = 0; e < 16; ++e)
#pragma unroll
      for (int j = 0; j < 4; ++j)
        ctxb[(orow0 + j) * 8192 + h * 512 + eh * 256 + e * 16 + lr] =
            f2bf(acc[m][e][j] * inv[j]);
  }
}

// ---------------- launch ----------------
extern "C" void kernel_launch(void* const* d_in, const int* in_sizes, int n_in,
                              void* d_out, int out_size, void* d_ws, size_t ws_size,
                              hipStream_t stream) {
  const float* x      = (const float*)d_in[0];
  const float* W_attn = (const float*)d_in[1];
  const float* W_out  = (const float*)d_in[2];
  const float* b_out  = (const float*)d_in[3];
  float* out = (float*)d_out;
  char* ws = (char*)d_ws;

  if (ws_size < 158334976u) return;  // need ~151MB scratch

  float* sinT = (float*)(ws + 0);
  float* cosT = (float*)(ws + 524288);
  u16* xb   = (u16*)(ws + 1048576);    // 16MB   (dead after GEMM1)
  u16* WbT  = (u16*)(ws + 17825792);   // 18MB   (dead after GEMM1)
  u16* qkvb = (u16*)(ws + 36700160);   // 36MB
  u16* vT   = (u16*)(ws + 74448896);   // 16MB
  u16* ctxb = (u16*)(ws + 91226112);   // 64MB
  u16* WobT = (u16*)(ws + 1048576);    // 32MB, reuses xb+WbT region post-GEMM1

  rope_tables<<<512, 256, 0, stream>>>(sinT, cosT);
  cast_f32_bf16<<<8192, 256, 0, stream>>>(x, xb);
  transpose_cast<<<dim3(144, 64), dim3(32, 8), 0, stream>>>(W_attn, WbT, 2048, 4608);
  gemm_bt<0><<<dim3(36, 32), 256, 0, stream>>>(xb, WbT, nullptr, qkvb, nullptr, 4608, 2048);
  rope_kernel<<<20480, 256, 0, stream>>>(qkvb, sinT, cosT);
  vt_kernel<<<dim3(16, 64, 8), dim3(32, 8), 0, stream>>>(qkvb, vT);
  attn_kernel<<<512, 512, 0, stream>>>(qkvb, vT, ctxb);
  transpose_cast<<<dim3(64, 256), dim3(32, 8), 0, stream>>>(W_out, WobT, 8192, 2048);
  gemm_bt<1><<<dim3(16, 32), 256, 0, stream>>>(ctxb, WobT, out, nullptr, b_out, 2048, 8192);
}

// Round 3
// 645.540 us; speedup vs baseline: 1.5083x; 1.2572x over previous
//
#include <hip/hip_runtime.h>

typedef unsigned short u16;
typedef float f32x4 __attribute__((ext_vector_type(4)));
typedef __bf16 bf16x8 __attribute__((ext_vector_type(8)));

#define DEV static __device__ __forceinline__

DEV u16 f2bf(float f) {
  union { float f; unsigned u; } c; c.f = f;
  unsigned u = c.u;
  u += 0x7fffu + ((u >> 16) & 1u);   // RNE; inputs are normal floats
  return (u16)(u >> 16);
}
DEV float bf2f(u16 h) {
  union { float f; unsigned u; } c; c.u = ((unsigned)h) << 16;
  return c.f;
}
DEV f32x4 MFMA(bf16x8 a, bf16x8 b, f32x4 c) {
  return __builtin_amdgcn_mfma_f32_16x16x32_bf16(a, b, c, 0, 0, 0);
}
DEV unsigned cvt_pk_bf16(float a, float b) {   // low16 = a, high16 = b (RNE)
  unsigned r;
  asm("v_cvt_pk_bf16_f32 %0, %1, %2" : "=v"(r) : "v"(a), "v"(b));
  return r;
}
DEV void glds16(const void* src, void* lds) {   // async global->LDS, 16B/lane
  __builtin_amdgcn_global_load_lds(
      (__attribute__((address_space(1))) void*)src,
      (__attribute__((address_space(3))) void*)lds, 16, 0, 0);
}

// ---------------- constants ----------------
// B=2 L=2048 DM=2048 H=16 KV=4 GROUP=4 DK=128 DV=512
// qkv row layout: [0,2048) q (16x128) | [2048,2560) k (4x128) | [2560,4608) v (4x512)

// ---------------- RoPE tables ----------------
__global__ void rope_tables(float* __restrict__ sinT, float* __restrict__ cosT) {
  int idx = blockIdx.x * 256 + threadIdx.x;     // 2048*64
  int l = idx >> 6, i = idx & 63;
  float inv = __expf(-((float)(2 * i) / 128.0f) * 9.210340371976184f); // 10000^(-2i/128)
  float ang = (float)l * inv;
  sinT[idx] = sinf(ang);
  cosT[idx] = cosf(ang);
}

// ---------------- cast x -> bf16 ----------------
__global__ void cast_f32_bf16(const float* __restrict__ in, u16* __restrict__ out) {
  int i = (blockIdx.x * 256 + threadIdx.x) * 4;
  float4 v = *(const float4*)(in + i);
  ushort4 o;
  o.x = f2bf(v.x); o.y = f2bf(v.y); o.z = f2bf(v.z); o.w = f2bf(v.w);
  *(ushort4*)(out + i) = o;
}

// ---------------- transpose + cast: fp32 [R][C] -> bf16 [C][R] ----------------
__global__ void transpose_cast(const float* __restrict__ in, u16* __restrict__ out,
                               int R, int C) {
  __shared__ u16 tile[32][33];
  int c0 = blockIdx.x * 32, r0 = blockIdx.y * 32;
  int tx = threadIdx.x, ty = threadIdx.y;   // 32 x 8
  for (int i = 0; i < 32; i += 8)
    tile[ty + i][tx] = f2bf(in[(size_t)(r0 + ty + i) * C + c0 + tx]);
  __syncthreads();
  for (int i = 0; i < 32; i += 8)
    out[(size_t)(c0 + ty + i) * R + r0 + tx] = tile[tx][ty + i];
}

// ---------------- GEMM: C[M][N] = A[M][K](bf16) @ Bt[N][K](bf16)^T ----------------
// 128x128 tile, BK=32, 256 thr. global_load_lds staging (m97 pattern):
// linear LDS dest, source slot pre-swizzled with the same involution the reads use.
template <int WRITE_F32>
__global__ __launch_bounds__(256) void gemm_bt(
    const u16* __restrict__ A, const u16* __restrict__ Bt,
    float* __restrict__ Cf, u16* __restrict__ Cb,
    const float* __restrict__ bias, int N, int K) {
  __shared__ __align__(16) u16 lA[128 * 32];
  __shared__ __align__(16) u16 lB[128 * 32];
  const int bn = blockIdx.x, bm = blockIdx.y;
  const int t = threadIdx.x, w = t >> 6, l = t & 63;
  const int wr = w >> 1, wc = w & 1;
  const int lr = l & 15, lg = l >> 4;

  f32x4 zero = {0.f, 0.f, 0.f, 0.f};
  f32x4 acc[4][4];
#pragma unroll
  for (int m = 0; m < 4; ++m)
#pragma unroll
    for (int n = 0; n < 4; ++n) acc[m][n] = zero;

  const int lrow = l >> 2, lslot = l & 3;    // within one 1KB load: 16 rows x 4 slots
  const size_t aBase = (size_t)(bm * 128) * K;
  const size_t bBase = (size_t)(bn * 128) * K;

  for (int k0 = 0; k0 < K; k0 += 32) {
    __syncthreads();
#pragma unroll
    for (int i = 0; i < 2; ++i) {
      int R = w * 16 + i * 64;               // wave-uniform base row
      int row = R + lrow;
      int sg = (lslot ^ (row & 3)) * 8;      // pre-swizzled source slot
      glds16(A + aBase + (size_t)row * K + k0 + sg, (u16*)lA + R * 32);
      glds16(Bt + bBase + (size_t)row * K + k0 + sg, (u16*)lB + R * 32);
    }
    __syncthreads();                         // compiler drains vmcnt here

    bf16x8 af[4], bf[4];
#pragma unroll
    for (int m = 0; m < 4; ++m) {
      int row = wr * 64 + m * 16 + lr;
      int sw = (lg ^ (row & 3)) & 3;
      af[m] = *(const bf16x8*)((char*)lA + row * 64 + sw * 16);
    }
#pragma unroll
    for (int n = 0; n < 4; ++n) {
      int row = wc * 64 + n * 16 + lr;
      int sw = (lg ^ (row & 3)) & 3;
      bf[n] = *(const bf16x8*)((char*)lB + row * 64 + sw * 16);
    }
#pragma unroll
    for (int m = 0; m < 4; ++m)
#pragma unroll
      for (int n = 0; n < 4; ++n)
        acc[m][n] = MFMA(af[m], bf[n], acc[m][n]);
  }

#pragma unroll
  for (int m = 0; m < 4; ++m) {
#pragma unroll
    for (int n = 0; n < 4; ++n) {
      int col = bn * 128 + wc * 64 + n * 16 + lr;
      float bv = WRITE_F32 ? bias[col] : 0.f;
#pragma unroll
      for (int j = 0; j < 4; ++j) {
        size_t rowg = (size_t)(bm * 128 + wr * 64 + m * 16 + lg * 4 + j);
        float v = acc[m][n][j];
        if (WRITE_F32) Cf[rowg * N + col] = v + bv;
        else           Cb[rowg * N + col] = f2bf(v);
      }
    }
  }
}

// ---------------- RoPE in-place on bf16 qkv; q heads pre-scaled by 1/sqrt(dk) ----
__global__ void rope_kernel(u16* __restrict__ qkv, const float* __restrict__ sinT,
                            const float* __restrict__ cosT) {
  int idx = blockIdx.x * 256 + threadIdx.x;   // 4096 rows * 20 heads * 64
  int d = idx & 63;
  int rh = idx >> 6;
  int head = rh % 20;
  int row = rh / 20;
  int lpos = row & 2047;
  int col = head < 16 ? head * 128 : 2048 + (head - 16) * 128;
  float sc = head < 16 ? 0.08838834764831845f : 1.0f;   // fold 1/sqrt(128) into Q
  u16* p = qkv + (size_t)row * 4608 + col;
  float x1 = bf2f(p[d]), x2 = bf2f(p[d + 64]);
  float c = cosT[lpos * 64 + d], s = sinT[lpos * 64 + d];
  p[d]      = f2bf((x1 * c - x2 * s) * sc);
  p[d + 64] = f2bf((x2 * c + x1 * s) * sc);
}

// ---------------- V^T builder: vT[(b*4+kv)*512 + e][l] = qkv[b*2048+l][2560+kv*512+e] ----
__global__ void vt_kernel(const u16* __restrict__ qkv, u16* __restrict__ vT) {
  __shared__ u16 tile[32][33];
  int bkv = blockIdx.z;
  int b = bkv >> 2, kv = bkv & 3;
  int e0 = blockIdx.x * 32, l0 = blockIdx.y * 32;
  const u16* src = qkv + (size_t)(b * 2048) * 4608 + 2560 + kv * 512;
  int tx = threadIdx.x, ty = threadIdx.y;   // 32 x 8
  for (int i = 0; i < 32; i += 8)
    tile[ty + i][tx] = src[(size_t)(l0 + ty + i) * 4608 + e0 + tx];
  __syncthreads();
  u16* dst = vT + (size_t)(bkv * 512) * 2048;
  for (int i = 0; i < 32; i += 8)
    dst[(size_t)(e0 + ty + i) * 2048 + l0 + tx] = tile[tx][ty + i];
}

// ---------------- flash attention v3: swapped QK^T, lane-local softmax ----------------
// 512 blocks: pg=wg&7 -> (kvg,b) panel (XCD-grouped), qt=wg>>3.
// 512 thr = 8 waves: wave -> head h4=w>>1, e-half eh=w&1; 32 q-rows x 256 e-cols.
// S^T = mfma(K, Q): lane holds P for q=lr, k in {4lg..4lg+3, 16+4lg..19+4lg}.
// PV A-frag packed in-lane (k-permuted); V frag read as two ds_read_b64 to match.
__global__ __launch_bounds__(512, 2) void attn_kernel(
    const u16* __restrict__ qkv, const u16* __restrict__ vT,
    u16* __restrict__ ctxb) {
  const int wg = blockIdx.x;
  const int pg = wg & 7, qt = wg >> 3;
  const int kvg = pg & 3, b = pg >> 2;
  const int t = threadIdx.x, w = t >> 6, l = t & 63;
  const int lr = l & 15, lg = l >> 4;
  const int h4 = w >> 1, eh = w & 1;
  const int h = kvg * 4 + h4;

  __shared__ __align__(16) u16 lK[32 * 128];   // 8KB  (16-slot swizzle)
  __shared__ __align__(16) u16 lV[512 * 32];   // 32KB (packed [256][128B], 8-slot swizzle)

  f32x4 zero = {0.f, 0.f, 0.f, 0.f};

  // Q fragments (pre-scaled by 1/sqrt(dk) in rope): qf[m][dc]
  bf16x8 qf[2][4];
  const size_t qbase = (size_t)(b * 2048 + qt * 32);
#pragma unroll
  for (int m = 0; m < 2; ++m)
#pragma unroll
    for (int dc = 0; dc < 4; ++dc)
      qf[m][dc] = *(const bf16x8*)(qkv + (qbase + m * 16 + lr) * 4608 + h * 128 + dc * 32 + lg * 8);

  f32x4 acc[2][16];
#pragma unroll
  for (int m = 0; m < 2; ++m)
#pragma unroll
    for (int e = 0; e < 16; ++e) acc[m][e] = zero;
  float m_r[2] = {-1e30f, -1e30f};   // per-lane state for q = lr (replicated x4 lg)
  float l_r[2] = {0.f, 0.f};

  const size_t kbase = (size_t)(b * 2048) * 4608 + 2048 + kvg * 128;
  const size_t vbase = (size_t)((b * 4 + kvg) * 512) * 2048;

  // staging addresses (lane-constant)
  const u16* vsrc = vT + vbase + (size_t)(t >> 2) * 2048 + (t & 3) * 8;
  const u16* ksrc = qkv + kbase + (size_t)(t >> 4) * 4608 + (t & 15) * 8;
  char* vdst;
  { int slot = ((t >> 2) & 1) * 4 + (t & 3);
    int sw = slot ^ ((t >> 3) & 7);
    vdst = (char*)lV + (t >> 3) * 128 + sw * 16; }
  char* kdst;
  { int s = t & 15, r7 = (t >> 4) & 7;
    int sw = (s & 8) | ((s ^ r7) & 7);
    kdst = (char*)lK + (t >> 4) * 256 + sw * 16; }

  // PV V-fragment read offsets (lane-constant): two 8B reads per e-tile,
  // rows kv = 4lg..4lg+3 (lo) and 16+4lg..19+4lg (hi), col e = eh*256+et*16+lr.
  const int pr7 = (lr >> 1) & 7;
  const int sw1 = (((lr & 1) * 4) + (lg >> 1)) ^ pr7;
  const int sw2 = (((lr & 1) * 4) + 2 + (lg >> 1)) ^ pr7;
  const int vo_base = (eh * 128 + (lr >> 1)) * 128 + (lg & 1) * 8;
  const int vo1 = vo_base + sw1 * 16;
  const int vo2 = vo_base + sw2 * 16;

  // prologue: prefetch tile kv0=0 into regs
  bf16x8 vreg[4], kreg;
#pragma unroll
  for (int i = 0; i < 4; ++i) vreg[i] = *(const bf16x8*)(vsrc + (size_t)i * 262144);
  kreg = *(const bf16x8*)(ksrc);

  for (int kv0 = 0; kv0 < 2048; kv0 += 32) {
    __syncthreads();                       // prior compute done reading LDS
#pragma unroll
    for (int i = 0; i < 4; ++i) *(bf16x8*)(vdst + i * 8192) = vreg[i];
    *(bf16x8*)(kdst) = kreg;
    if (kv0 + 32 < 2048) {                 // prefetch next tile (hides under compute)
#pragma unroll
      for (int i = 0; i < 4; ++i)
        vreg[i] = *(const bf16x8*)(vsrc + (kv0 + 32) + (size_t)i * 262144);
      kreg = *(const bf16x8*)(ksrc + (size_t)(kv0 + 32) * 4608);
    }
    __syncthreads();                       // tile staged

    // ---- S^T = K Q^T : sT[kt][m], lane holds S^T[16kt+4lg+j][q=lr] ----
    f32x4 sT[2][2];
    sT[0][0] = zero; sT[0][1] = zero; sT[1][0] = zero; sT[1][1] = zero;
#pragma unroll
    for (int dc = 0; dc < 4; ++dc) {
      int slot = dc * 4 + lg;
      int sw = (slot & 8) | ((slot ^ (lr & 7)) & 7);
#pragma unroll
      for (int kt = 0; kt < 2; ++kt) {
        bf16x8 kf = *(const bf16x8*)((char*)lK + (kt * 16 + lr) * 256 + sw * 16);
        sT[kt][0] = MFMA(kf, qf[0][dc], sT[kt][0]);   // swapped operands
        sT[kt][1] = MFMA(kf, qf[1][dc], sT[kt][1]);
      }
    }

    // ---- in-lane online softmax (q = lr) ----
    float rmax[2];
#pragma unroll
    for (int m = 0; m < 2; ++m) {
      float a0 = fmaxf(fmaxf(sT[0][m][0], sT[0][m][1]), fmaxf(sT[0][m][2], sT[0][m][3]));
      float a1 = fmaxf(fmaxf(sT[1][m][0], sT[1][m][1]), fmaxf(sT[1][m][2], sT[1][m][3]));
      float r = fmaxf(a0, a1);
      r = fmaxf(r, __shfl_xor(r, 16));
      r = fmaxf(r, __shfl_xor(r, 32));
      rmax[m] = r;
    }
    bool need = (rmax[0] > m_r[0] + 8.f) || (rmax[1] > m_r[1] + 8.f);
    if (__any(need)) {                      // defer-max: rescale only on growth
#pragma unroll
      for (int m = 0; m < 2; ++m) {
        float mn = fmaxf(m_r[m], rmax[m]);
        float al = __expf(m_r[m] - mn);
        m_r[m] = mn; l_r[m] *= al;
        float alj[4];
#pragma unroll
        for (int j = 0; j < 4; ++j) alj[j] = __shfl(al, lg * 4 + j);  // C-row j
#pragma unroll
        for (int e = 0; e < 16; ++e)
#pragma unroll
          for (int j = 0; j < 4; ++j) acc[m][e][j] *= alj[j];
      }
    }

    bf16x8 pf[2];
#pragma unroll
    for (int m = 0; m < 2; ++m) {
      float p0 = __expf(sT[0][m][0] - m_r[m]), p1 = __expf(sT[0][m][1] - m_r[m]);
      float p2 = __expf(sT[0][m][2] - m_r[m]), p3 = __expf(sT[0][m][3] - m_r[m]);
      float p4 = __expf(sT[1][m][0] - m_r[m]), p5 = __expf(sT[1][m][1] - m_r[m]);
      float p6 = __expf(sT[1][m][2] - m_r[m]), p7 = __expf(sT[1][m][3] - m_r[m]);
      float s = ((p0 + p1) + (p2 + p3)) + ((p4 + p5) + (p6 + p7));
      s += __shfl_xor(s, 16);
      s += __shfl_xor(s, 32);
      l_r[m] += s;
      union { bf16x8 v; unsigned wd[4]; } u;
      u.wd[0] = cvt_pk_bf16(p0, p1);
      u.wd[1] = cvt_pk_bf16(p2, p3);
      u.wd[2] = cvt_pk_bf16(p4, p5);
      u.wd[3] = cvt_pk_bf16(p6, p7);
      pf[m] = u.v;
    }

    // ---- PV: vf = k-permuted V frag (two b64), reused across m ----
#pragma unroll
    for (int e = 0; e < 16; ++e) {
      typedef __bf16 bf16x4 __attribute__((ext_vector_type(4)));
      bf16x4 lo = *(const bf16x4*)((char*)lV + vo1 + e * 1024);
      bf16x4 hi = *(const bf16x4*)((char*)lV + vo2 + e * 1024);
      bf16x8 vf = __builtin_shufflevector(lo, hi, 0, 1, 2, 3, 4, 5, 6, 7);
      acc[0][e] = MFMA(pf[0], vf, acc[0][e]);
      acc[1][e] = MFMA(pf[1], vf, acc[1][e]);
    }
  }

  // ---- epilogue ----
#pragma unroll
  for (int m = 0; m < 2; ++m) {
    float linv[4];
#pragma unroll
    for (int j = 0; j < 4; ++j) linv[j] = 1.0f / __shfl(l_r[m], lg * 4 + j);
    const size_t orow0 = qbase + m * 16 + lg * 4;
#pragma unroll
    for (int e = 0; e < 16; ++e)
#pragma unroll
      for (int j = 0; j < 4; ++j)
        ctxb[(orow0 + j) * 8192 + h * 512 + eh * 256 + e * 16 + lr] =
            f2bf(acc[m][e][j] * linv[j]);
  }
}

// ---------------- launch ----------------
extern "C" void kernel_launch(void* const* d_in, const int* in_sizes, int n_in,
                              void* d_out, int out_size, void* d_ws, size_t ws_size,
                              hipStream_t stream) {
  const float* x      = (const float*)d_in[0];
  const float* W_attn = (const float*)d_in[1];
  const float* W_out  = (const float*)d_in[2];
  const float* b_out  = (const float*)d_in[3];
  float* out = (float*)d_out;
  char* ws = (char*)d_ws;

  if (ws_size < 158334976u) return;  // need ~151MB scratch

  float* sinT = (float*)(ws + 0);
  float* cosT = (float*)(ws + 524288);
  u16* xb   = (u16*)(ws + 1048576);    // 16MB   (dead after GEMM1)
  u16* WbT  = (u16*)(ws + 17825792);   // 18MB   (dead after GEMM1)
  u16* qkvb = (u16*)(ws + 36700160);   // 36MB
  u16* vT   = (u16*)(ws + 74448896);   // 16MB
  u16* ctxb = (u16*)(ws + 91226112);   // 64MB
  u16* WobT = (u16*)(ws + 1048576);    // 32MB, reuses xb+WbT region post-GEMM1

  rope_tables<<<512, 256, 0, stream>>>(sinT, cosT);
  cast_f32_bf16<<<8192, 256, 0, stream>>>(x, xb);
  transpose_cast<<<dim3(144, 64), dim3(32, 8), 0, stream>>>(W_attn, WbT, 2048, 4608);
  gemm_bt<0><<<dim3(36, 32), 256, 0, stream>>>(xb, WbT, nullptr, qkvb, nullptr, 4608, 2048);
  rope_kernel<<<20480, 256, 0, stream>>>(qkvb, sinT, cosT);
  vt_kernel<<<dim3(16, 64, 8), dim3(32, 8), 0, stream>>>(qkvb, vT);
  attn_kernel<<<512, 512, 0, stream>>>(qkvb, vT, ctxb);
  transpose_cast<<<dim3(64, 256), dim3(32, 8), 0, stream>>>(W_out, WobT, 8192, 2048);
  gemm_bt<1><<<dim3(16, 32), 256, 0, stream>>>(ctxb, WobT, out, nullptr, b_out, 2048, 8192);
}

// Round 4
// 629.461 us; speedup vs baseline: 1.5469x; 1.0255x over previous
//
#include <hip/hip_runtime.h>

typedef unsigned short u16;
typedef float f32x4 __attribute__((ext_vector_type(4)));
typedef __bf16 bf16x8 __attribute__((ext_vector_type(8)));

#define DEV static __device__ __forceinline__

DEV u16 f2bf(float f) {
  union { float f; unsigned u; } c; c.f = f;
  unsigned u = c.u;
  u += 0x7fffu + ((u >> 16) & 1u);   // RNE; inputs are normal floats
  return (u16)(u >> 16);
}
DEV float bf2f(u16 h) {
  union { float f; unsigned u; } c; c.u = ((unsigned)h) << 16;
  return c.f;
}
DEV f32x4 MFMA(bf16x8 a, bf16x8 b, f32x4 c) {
  return __builtin_amdgcn_mfma_f32_16x16x32_bf16(a, b, c, 0, 0, 0);
}
DEV unsigned cvt_pk_bf16(float a, float b) {   // low16 = a, high16 = b (RNE)
  unsigned r;
  asm("v_cvt_pk_bf16_f32 %0, %1, %2" : "=v"(r) : "v"(a), "v"(b));
  return r;
}
DEV float ex2(float x) { return __builtin_amdgcn_exp2f(x); }
DEV void glds16(const void* src, void* lds) {   // async global->LDS, 16B/lane
  __builtin_amdgcn_global_load_lds(
      (__attribute__((address_space(1))) void*)src,
      (__attribute__((address_space(3))) void*)lds, 16, 0, 0);
}

// ---------------- constants ----------------
// B=2 L=2048 DM=2048 H=16 KV=4 GROUP=4 DK=128 DV=512
// qkv row layout: [0,2048) q (16x128) | [2048,2560) k (4x128) | [2560,4608) v (4x512)

// ---------------- RoPE tables ----------------
__global__ void rope_tables(float* __restrict__ sinT, float* __restrict__ cosT) {
  int idx = blockIdx.x * 256 + threadIdx.x;     // 2048*64
  int l = idx >> 6, i = idx & 63;
  float inv = __expf(-((float)(2 * i) / 128.0f) * 9.210340371976184f); // 10000^(-2i/128)
  float ang = (float)l * inv;
  sinT[idx] = sinf(ang);
  cosT[idx] = cosf(ang);
}

// ---------------- cast x -> bf16 ----------------
__global__ void cast_f32_bf16(const float* __restrict__ in, u16* __restrict__ out) {
  int i = (blockIdx.x * 256 + threadIdx.x) * 4;
  float4 v = *(const float4*)(in + i);
  ushort4 o;
  o.x = f2bf(v.x); o.y = f2bf(v.y); o.z = f2bf(v.z); o.w = f2bf(v.w);
  *(ushort4*)(out + i) = o;
}

// ---------------- transpose + cast: fp32 [R][C] -> bf16 [C][R] ----------------
__global__ void transpose_cast(const float* __restrict__ in, u16* __restrict__ out,
                               int R, int C) {
  __shared__ u16 tile[32][33];
  int c0 = blockIdx.x * 32, r0 = blockIdx.y * 32;
  int tx = threadIdx.x, ty = threadIdx.y;   // 32 x 8
  for (int i = 0; i < 32; i += 8)
    tile[ty + i][tx] = f2bf(in[(size_t)(r0 + ty + i) * C + c0 + tx]);
  __syncthreads();
  for (int i = 0; i < 32; i += 8)
    out[(size_t)(c0 + ty + i) * R + r0 + tx] = tile[tx][ty + i];
}

// ---------------- GEMM: C[M][N] = A[M][K](bf16) @ Bt[N][K](bf16)^T ----------------
// 128x128 tile, BK=32, 256 thr. global_load_lds staging (m97 pattern).
template <int WRITE_F32>
__global__ __launch_bounds__(256) void gemm_bt(
    const u16* __restrict__ A, const u16* __restrict__ Bt,
    float* __restrict__ Cf, u16* __restrict__ Cb,
    const float* __restrict__ bias, int N, int K) {
  __shared__ __align__(16) u16 lA[128 * 32];
  __shared__ __align__(16) u16 lB[128 * 32];
  const int bn = blockIdx.x, bm = blockIdx.y;
  const int t = threadIdx.x, w = t >> 6, l = t & 63;
  const int wr = w >> 1, wc = w & 1;
  const int lr = l & 15, lg = l >> 4;

  f32x4 zero = {0.f, 0.f, 0.f, 0.f};
  f32x4 acc[4][4];
#pragma unroll
  for (int m = 0; m < 4; ++m)
#pragma unroll
    for (int n = 0; n < 4; ++n) acc[m][n] = zero;

  const int lrow = l >> 2, lslot = l & 3;    // within one 1KB load: 16 rows x 4 slots
  const size_t aBase = (size_t)(bm * 128) * K;
  const size_t bBase = (size_t)(bn * 128) * K;

  for (int k0 = 0; k0 < K; k0 += 32) {
    __syncthreads();
#pragma unroll
    for (int i = 0; i < 2; ++i) {
      int R = w * 16 + i * 64;               // wave-uniform base row
      int row = R + lrow;
      int sg = (lslot ^ (row & 3)) * 8;      // pre-swizzled source slot
      glds16(A + aBase + (size_t)row * K + k0 + sg, (u16*)lA + R * 32);
      glds16(Bt + bBase + (size_t)row * K + k0 + sg, (u16*)lB + R * 32);
    }
    __syncthreads();                         // compiler drains vmcnt here

    bf16x8 af[4], bf[4];
#pragma unroll
    for (int m = 0; m < 4; ++m) {
      int row = wr * 64 + m * 16 + lr;
      int sw = (lg ^ (row & 3)) & 3;
      af[m] = *(const bf16x8*)((char*)lA + row * 64 + sw * 16);
    }
#pragma unroll
    for (int n = 0; n < 4; ++n) {
      int row = wc * 64 + n * 16 + lr;
      int sw = (lg ^ (row & 3)) & 3;
      bf[n] = *(const bf16x8*)((char*)lB + row * 64 + sw * 16);
    }
#pragma unroll
    for (int m = 0; m < 4; ++m)
#pragma unroll
      for (int n = 0; n < 4; ++n)
        acc[m][n] = MFMA(af[m], bf[n], acc[m][n]);
  }

#pragma unroll
  for (int m = 0; m < 4; ++m) {
#pragma unroll
    for (int n = 0; n < 4; ++n) {
      int col = bn * 128 + wc * 64 + n * 16 + lr;
      float bv = WRITE_F32 ? bias[col] : 0.f;
#pragma unroll
      for (int j = 0; j < 4; ++j) {
        size_t rowg = (size_t)(bm * 128 + wr * 64 + m * 16 + lg * 4 + j);
        float v = acc[m][n][j];
        if (WRITE_F32) Cf[rowg * N + col] = v + bv;
        else           Cb[rowg * N + col] = f2bf(v);
      }
    }
  }
}

// ---------------- RoPE in-place; q heads pre-scaled by log2(e)/sqrt(dk) ----
__global__ void rope_kernel(u16* __restrict__ qkv, const float* __restrict__ sinT,
                            const float* __restrict__ cosT) {
  int idx = blockIdx.x * 256 + threadIdx.x;   // 4096 rows * 20 heads * 64
  int d = idx & 63;
  int rh = idx >> 6;
  int head = rh % 20;
  int row = rh / 20;
  int lpos = row & 2047;
  int col = head < 16 ? head * 128 : 2048 + (head - 16) * 128;
  // fold 1/sqrt(128) * log2(e) into Q -> softmax runs in exp2 domain
  float sc = head < 16 ? 0.12751743561938476f : 1.0f;
  u16* p = qkv + (size_t)row * 4608 + col;
  float x1 = bf2f(p[d]), x2 = bf2f(p[d + 64]);
  float c = cosT[lpos * 64 + d], s = sinT[lpos * 64 + d];
  p[d]      = f2bf((x1 * c - x2 * s) * sc);
  p[d + 64] = f2bf((x2 * c + x1 * s) * sc);
}

// ---------------- V^T builder with k-permutation ----------------
// vTp[(b*4+kv)*512 + e][g*32 + pi(k)] = V[g*32+k][e],
// pi(k) = ((k>>2)&3)*8 + ((k>>4)&1)*4 + (k&3)  (bijective bit permute)
// so that PV B-fragments (one b128/lane) arrive in the in-lane P k-order.
__global__ void vt_kernel(const u16* __restrict__ qkv, u16* __restrict__ vT) {
  __shared__ u16 tile[32][33];
  int bkv = blockIdx.z;
  int b = bkv >> 2, kv = bkv & 3;
  int e0 = blockIdx.x * 32, l0 = blockIdx.y * 32;
  const u16* src = qkv + (size_t)(b * 2048) * 4608 + 2560 + kv * 512;
  int tx = threadIdx.x, ty = threadIdx.y;   // 32 x 8
  for (int i = 0; i < 32; i += 8)
    tile[ty + i][tx] = src[(size_t)(l0 + ty + i) * 4608 + e0 + tx];
  __syncthreads();
  u16* dst = vT + (size_t)(bkv * 512) * 2048;
  int pi = ((tx >> 2) & 3) * 8 + ((tx >> 4) & 1) * 4 + (tx & 3);
  for (int i = 0; i < 32; i += 8)
    dst[(size_t)(e0 + ty + i) * 2048 + l0 + pi] = tile[tx][ty + i];
}

// ---------------- flash attention v4 ----------------
// 512 blocks: pg=wg&7 -> (kvg,b) panel (XCD-grouped), qt=wg>>3.
// 512 thr = 8 waves: wave -> head h4=w>>1, e-half eh=w&1; 32 q-rows x 256 e-cols.
// Swapped QK^T (lane-local softmax, exp2 domain); glds16 staging into
// double-buffered LDS (80KB), one barrier/iter; PV = single b128/e-tile
// (R2-proven swizzle) against pi-permuted V.
__global__ __launch_bounds__(512, 2) void attn_kernel(
    const u16* __restrict__ qkv, const u16* __restrict__ vT,
    u16* __restrict__ ctxb) {
  const int wg = blockIdx.x;
  const int pg = wg & 7, qt = wg >> 3;
  const int kvg = pg & 3, b = pg >> 2;
  const int t = threadIdx.x, w = t >> 6, l = t & 63;
  const int lr = l & 15, lg = l >> 4;
  const int h4 = w >> 1, eh = w & 1;
  const int h = kvg * 4 + h4;

  __shared__ __align__(16) u16 lK[2][32 * 128];   // 2 x 8KB
  __shared__ __align__(16) u16 lV[2][256 * 64];   // 2 x 32KB, rows of 128B

  f32x4 zero = {0.f, 0.f, 0.f, 0.f};

  // Q fragments (pre-scaled by log2e/sqrt(dk) in rope)
  bf16x8 qf[2][4];
  const size_t qbase = (size_t)(b * 2048 + qt * 32);
#pragma unroll
  for (int m = 0; m < 2; ++m)
#pragma unroll
    for (int dc = 0; dc < 4; ++dc)
      qf[m][dc] = *(const bf16x8*)(qkv + (qbase + m * 16 + lr) * 4608 + h * 128 + dc * 32 + lg * 8);

  f32x4 acc[2][16];
#pragma unroll
  for (int m = 0; m < 2; ++m)
#pragma unroll
    for (int e = 0; e < 16; ++e) acc[m][e] = zero;
  float m_r[2] = {-1e30f, -1e30f};   // log2-domain running max (per-lane q = lr)
  float l_r[2] = {0.f, 0.f};

  const size_t kbase = (size_t)(b * 2048) * 4608 + 2048 + kvg * 128;
  const size_t vbase = (size_t)((b * 4 + kvg) * 512) * 2048;

  // staging sources (lane-constant; LDS dest linear, source pre-swizzled)
  const int krow = t >> 4;                                  // 0..31
  const int kp = t & 15;
  const int ks = (kp & 8) | ((kp ^ (krow & 7)) & 7);        // logical 16B slot
  const u16* ksrc0 = qkv + kbase + (size_t)krow * 4608 + ks * 8;
  const int vs = (t & 7) ^ ((t >> 3) & 7);                  // logical slot
  const int ve0 = (t >> 3) * 2 + (vs >> 2);                 // e row (round 0)
  const u16* vsrc0 = vT + vbase + (size_t)ve0 * 2048 + (vs & 3) * 8;

  // PV fragment read offset (R2-proven pattern), bytes into lV[buf]
  const int vfoff = (eh * 128 + (lr >> 1)) * 128 +
                    (((((lr & 1) << 2) | lg) ^ ((lr >> 1) & 7)) << 4);

  auto stage = [&](int bi, int kv0) {
    glds16(ksrc0 + (size_t)kv0 * 4608, &lK[bi][t * 8]);
#pragma unroll
    for (int i = 0; i < 4; ++i)
      glds16(vsrc0 + kv0 + (size_t)i * 262144, &lV[bi][i * 4096 + t * 8]);
  };

  stage(0, 0);   // prologue

  for (int it = 0; it < 64; ++it) {
    const int cur = it & 1;
    __syncthreads();                         // drains cur-buffer loads
    if (it + 1 < 64) stage(cur ^ 1, 32 * (it + 1));   // in flight during compute
    const char* lKc = (const char*)lK[cur];
    const char* lVc = (const char*)lV[cur];

    // ---- S^T = K Q^T : lane holds S^T[16kt+4lg+j][q=lr] (log2 domain) ----
    f32x4 sT[2][2];
    sT[0][0] = zero; sT[0][1] = zero; sT[1][0] = zero; sT[1][1] = zero;
#pragma unroll
    for (int dc = 0; dc < 4; ++dc) {
      int slot = dc * 4 + lg;
      int sw = (slot & 8) | ((slot ^ (lr & 7)) & 7);
#pragma unroll
      for (int kt = 0; kt < 2; ++kt) {
        bf16x8 kf = *(const bf16x8*)(lKc + (kt * 16 + lr) * 256 + sw * 16);
        sT[kt][0] = MFMA(kf, qf[0][dc], sT[kt][0]);
        sT[kt][1] = MFMA(kf, qf[1][dc], sT[kt][1]);
      }
    }

    // ---- in-lane online softmax (exp2 domain) ----
    float rmax[2];
#pragma unroll
    for (int m = 0; m < 2; ++m) {
      float a0 = fmaxf(fmaxf(sT[0][m][0], sT[0][m][1]), fmaxf(sT[0][m][2], sT[0][m][3]));
      float a1 = fmaxf(fmaxf(sT[1][m][0], sT[1][m][1]), fmaxf(sT[1][m][2], sT[1][m][3]));
      float r = fmaxf(a0, a1);
      r = fmaxf(r, __shfl_xor(r, 16));
      r = fmaxf(r, __shfl_xor(r, 32));
      rmax[m] = r;
    }
    bool need = (rmax[0] > m_r[0] + 11.5f) || (rmax[1] > m_r[1] + 11.5f);
    if (__any(need)) {                      // defer-max (11.5 bits ~ 8 nats)
#pragma unroll
      for (int m = 0; m < 2; ++m) {
        float mn = fmaxf(m_r[m], rmax[m]);
        float al = ex2(m_r[m] - mn);
        m_r[m] = mn; l_r[m] *= al;
        float alj[4];
#pragma unroll
        for (int j = 0; j < 4; ++j) alj[j] = __shfl(al, lg * 4 + j);  // C-row j
#pragma unroll
        for (int e = 0; e < 16; ++e)
#pragma unroll
          for (int j = 0; j < 4; ++j) acc[m][e][j] *= alj[j];
      }
    }

    bf16x8 pf[2];
#pragma unroll
    for (int m = 0; m < 2; ++m) {
      float p0 = ex2(sT[0][m][0] - m_r[m]), p1 = ex2(sT[0][m][1] - m_r[m]);
      float p2 = ex2(sT[0][m][2] - m_r[m]), p3 = ex2(sT[0][m][3] - m_r[m]);
      float p4 = ex2(sT[1][m][0] - m_r[m]), p5 = ex2(sT[1][m][1] - m_r[m]);
      float p6 = ex2(sT[1][m][2] - m_r[m]), p7 = ex2(sT[1][m][3] - m_r[m]);
      float s = ((p0 + p1) + (p2 + p3)) + ((p4 + p5) + (p6 + p7));
      s += __shfl_xor(s, 16);
      s += __shfl_xor(s, 32);
      l_r[m] += s;
      union { bf16x8 v; unsigned wd[4]; } u;
      u.wd[0] = cvt_pk_bf16(p0, p1);
      u.wd[1] = cvt_pk_bf16(p2, p3);
      u.wd[2] = cvt_pk_bf16(p4, p5);
      u.wd[3] = cvt_pk_bf16(p6, p7);
      pf[m] = u.v;
    }

    // ---- PV: one b128 per e-tile (V pre-permuted to match pf k-order) ----
#pragma unroll
    for (int e = 0; e < 16; ++e) {
      bf16x8 vf = *(const bf16x8*)(lVc + vfoff + e * 1024);
      acc[0][e] = MFMA(pf[0], vf, acc[0][e]);
      acc[1][e] = MFMA(pf[1], vf, acc[1][e]);
    }
  }

  // ---- epilogue ----
#pragma unroll
  for (int m = 0; m < 2; ++m) {
    float linv[4];
#pragma unroll
    for (int j = 0; j < 4; ++j) linv[j] = 1.0f / __shfl(l_r[m], lg * 4 + j);
    const size_t orow0 = qbase + m * 16 + lg * 4;
#pragma unroll
    for (int e = 0; e < 16; ++e)
#pragma unroll
      for (int j = 0; j < 4; ++j)
        ctxb[(orow0 + j) * 8192 + h * 512 + eh * 256 + e * 16 + lr] =
            f2bf(acc[m][e][j] * linv[j]);
  }
}

// ---------------- launch ----------------
extern "C" void kernel_launch(void* const* d_in, const int* in_sizes, int n_in,
                              void* d_out, int out_size, void* d_ws, size_t ws_size,
                              hipStream_t stream) {
  const float* x      = (const float*)d_in[0];
  const float* W_attn = (const float*)d_in[1];
  const float* W_out  = (const float*)d_in[2];
  const float* b_out  = (const float*)d_in[3];
  float* out = (float*)d_out;
  char* ws = (char*)d_ws;

  if (ws_size < 158334976u) return;  // need ~151MB scratch

  float* sinT = (float*)(ws + 0);
  float* cosT = (float*)(ws + 524288);
  u16* xb   = (u16*)(ws + 1048576);    // 16MB   (dead after GEMM1)
  u16* WbT  = (u16*)(ws + 17825792);   // 18MB   (dead after GEMM1)
  u16* qkvb = (u16*)(ws + 36700160);   // 36MB
  u16* vT   = (u16*)(ws + 74448896);   // 16MB
  u16* ctxb = (u16*)(ws + 91226112);   // 64MB
  u16* WobT = (u16*)(ws + 1048576);    // 32MB, reuses xb+WbT region post-GEMM1

  rope_tables<<<512, 256, 0, stream>>>(sinT, cosT);
  cast_f32_bf16<<<8192, 256, 0, stream>>>(x, xb);
  transpose_cast<<<dim3(144, 64), dim3(32, 8), 0, stream>>>(W_attn, WbT, 2048, 4608);
  gemm_bt<0><<<dim3(36, 32), 256, 0, stream>>>(xb, WbT, nullptr, qkvb, nullptr, 4608, 2048);
  rope_kernel<<<20480, 256, 0, stream>>>(qkvb, sinT, cosT);
  vt_kernel<<<dim3(16, 64, 8), dim3(32, 8), 0, stream>>>(qkvb, vT);
  attn_kernel<<<512, 512, 0, stream>>>(qkvb, vT, ctxb);
  transpose_cast<<<dim3(64, 256), dim3(32, 8), 0, stream>>>(W_out, WobT, 8192, 2048);
  gemm_bt<1><<<dim3(16, 32), 256, 0, stream>>>(ctxb, WobT, out, nullptr, b_out, 2048, 8192);
}

// Round 6
// 571.647 us; speedup vs baseline: 1.7033x; 1.1011x over previous
//
#include <hip/hip_runtime.h>

typedef unsigned short u16;
typedef float f32x4 __attribute__((ext_vector_type(4)));
typedef __bf16 bf16x8 __attribute__((ext_vector_type(8)));

#define DEV static __device__ __forceinline__

DEV u16 f2bf(float f) {
  union { float f; unsigned u; } c; c.f = f;
  unsigned u = c.u;
  u += 0x7fffu + ((u >> 16) & 1u);   // RNE; inputs are normal floats
  return (u16)(u >> 16);
}
DEV float bf2f(u16 h) {
  union { float f; unsigned u; } c; c.u = ((unsigned)h) << 16;
  return c.f;
}
DEV f32x4 MFMA(bf16x8 a, bf16x8 b, f32x4 c) {
  return __builtin_amdgcn_mfma_f32_16x16x32_bf16(a, b, c, 0, 0, 0);
}
DEV unsigned cvt_pk_bf16(float a, float b) {   // low16 = a, high16 = b (RNE)
  unsigned r;
  asm("v_cvt_pk_bf16_f32 %0, %1, %2" : "=v"(r) : "v"(a), "v"(b));
  return r;
}
DEV float ex2(float x) { return __builtin_amdgcn_exp2f(x); }
DEV void glds16(const void* src, void* lds) {   // async global->LDS, 16B/lane
  __builtin_amdgcn_global_load_lds(
      (__attribute__((address_space(1))) void*)src,
      (__attribute__((address_space(3))) void*)lds, 16, 0, 0);
}
DEV void barrier_raw() {                        // raw s_barrier: NO vmcnt drain
  __builtin_amdgcn_sched_barrier(0);
  asm volatile("s_barrier" ::: "memory");
  __builtin_amdgcn_sched_barrier(0);
}
#define VMCNT(N)                                              \
  do {                                                        \
    asm volatile("s_waitcnt vmcnt(" #N ")" ::: "memory");     \
    __builtin_amdgcn_sched_barrier(0);                        \
  } while (0)

// ---------------- constants ----------------
// B=2 L=2048 DM=2048 H=16 KV=4 GROUP=4 DK=128 DV=512
// qkv row layout: [0,2048) q (16x128) | [2048,2560) k (4x128) | [2560,4608) v (4x512)

// ---------------- RoPE tables ----------------
__global__ void rope_tables(float* __restrict__ sinT, float* __restrict__ cosT) {
  int idx = blockIdx.x * 256 + threadIdx.x;     // 2048*64
  int l = idx >> 6, i = idx & 63;
  float inv = __expf(-((float)(2 * i) / 128.0f) * 9.210340371976184f); // 10000^(-2i/128)
  float ang = (float)l * inv;
  sinT[idx] = sinf(ang);
  cosT[idx] = cosf(ang);
}

// ---------------- cast x -> bf16 ----------------
__global__ void cast_f32_bf16(const float* __restrict__ in, u16* __restrict__ out) {
  int i = (blockIdx.x * 256 + threadIdx.x) * 4;
  float4 v = *(const float4*)(in + i);
  ushort4 o;
  o.x = f2bf(v.x); o.y = f2bf(v.y); o.z = f2bf(v.z); o.w = f2bf(v.w);
  *(ushort4*)(out + i) = o;
}

// ---------------- transpose + cast: fp32 [R][C] -> bf16 [C][R] ----------------
__global__ void transpose_cast(const float* __restrict__ in, u16* __restrict__ out,
                               int R, int C) {
  __shared__ u16 tile[32][33];
  int c0 = blockIdx.x * 32, r0 = blockIdx.y * 32;
  int tx = threadIdx.x, ty = threadIdx.y;   // 32 x 8
  for (int i = 0; i < 32; i += 8)
    tile[ty + i][tx] = f2bf(in[(size_t)(r0 + ty + i) * C + c0 + tx]);
  __syncthreads();
  for (int i = 0; i < 32; i += 8)
    out[(size_t)(c0 + ty + i) * R + r0 + tx] = tile[tx][ty + i];
}

// ================= GEMM1: qkv = xb @ WbT^T =================
// M=4096 K=2048 N=4608. BM=BN=256, BK=64 (2 kk-halves), 512 thr = 8 waves (2M x 4N).
// 8-phase counted-vmcnt schedule. Invariant: 12 loads outstanding at each VMCNT(8),
// which completes exactly the 4 loads of the (buf,kk) region read two phases later;
// every VMCNT is followed by s_barrier BEFORE any wave reads the certified region.
// Main loop: NT/2-1 iters, staging unconditional. Tail peeled with waits 8->4->0.
__global__ __launch_bounds__(512) void gemm1_8ph(const u16* __restrict__ A,
                                                 const u16* __restrict__ Bt,
                                                 u16* __restrict__ C) {
  constexpr int K = 2048, N = 4608, NT = 32;   // NT = K/64
  __shared__ __align__(16) u16 lA[2][2][8192];
  __shared__ __align__(16) u16 lB[2][2][8192];
  const int t = threadIdx.x, w = t >> 6, l = t & 63;
  const int lr = l & 15, lg = l >> 4;
  const int wr = w >> 2, wn = w & 3;
  const int swz = (blockIdx.x & 7) * 36 + (blockIdx.x >> 3);  // 288 blocks, XCD-chunked
  const int bm = swz & 15, bn = swz >> 4;                      // 16 x 18

  const size_t aBase = (size_t)(bm * 256) * K;
  const size_t bBase = (size_t)(bn * 256) * K;
  const int lslog = (t & 3) ^ ((t >> 3) & 3);     // staging: logical slot for linear dest
  const int r128 = t >> 2;
  const int aswz = (lg ^ ((lr >> 1) & 3)) << 4;   // frag-read physical slot byte offset

  auto stA = [&](int buf, int kk, int tile) {
#pragma unroll
    for (int i = 0; i < 2; ++i) {
      int row = i * 128 + r128;
      glds16(A + aBase + (size_t)row * K + tile * 64 + kk * 32 + lslog * 8,
             &lA[buf][kk][i * 4096 + t * 8]);
    }
  };
  auto stB = [&](int buf, int kk, int tile) {
#pragma unroll
    for (int i = 0; i < 2; ++i) {
      int row = i * 128 + r128;
      glds16(Bt + bBase + (size_t)row * K + tile * 64 + kk * 32 + lslog * 8,
             &lB[buf][kk][i * 4096 + t * 8]);
    }
  };

  f32x4 acc[8][4];
#pragma unroll
  for (int f = 0; f < 8; ++f)
#pragma unroll
    for (int g = 0; g < 4; ++g) acc[f][g] = f32x4{0.f, 0.f, 0.f, 0.f};

  // prologue: 12 loads out; vmcnt(8) completes (0,0,t0); barrier certifies it.
  stA(0, 0, 0); stB(0, 0, 0); stA(0, 1, 0); stB(0, 1, 0); stA(1, 0, 1); stB(1, 0, 1);
  VMCNT(8);
  barrier_raw();

  // phase: reads certified region, issues staging, computes. NO trailing sync here;
  // caller appends [VMCNT] + barrier.
  auto PH = [&](int buf, int kk, int mh, auto&& st) {
    bf16x8 af[4], bb[4];
    const char* pA = (const char*)lA[buf][kk];
    const char* pB = (const char*)lB[buf][kk];
#pragma unroll
    for (int f = 0; f < 4; ++f) {
      af[f] = *(const bf16x8*)(pA + (wr * 128 + (mh * 4 + f) * 16 + lr) * 64 + aswz);
      bb[f] = *(const bf16x8*)(pB + (wn * 64 + f * 16 + lr) * 64 + aswz);
    }
    st();
    __builtin_amdgcn_s_setprio(1);
#pragma unroll
    for (int f = 0; f < 4; ++f)
#pragma unroll
      for (int g = 0; g < 4; ++g)
        acc[mh * 4 + f][g] = MFMA(af[f], bb[g], acc[mh * 4 + f][g]);
    __builtin_amdgcn_s_setprio(0);
  };
  auto NOST = [] {};

  for (int i = 0; i < NT / 2 - 1; ++i) {
    const int t1 = 2 * i + 1, t2 = 2 * i + 2, t3 = 2 * i + 3;
    PH(0, 0, 0, [&] { stA(1, 1, t1); });            barrier_raw();
    PH(0, 0, 1, [&] { stB(1, 1, t1); }); VMCNT(8);  barrier_raw();
    PH(0, 1, 0, [&] { stA(0, 0, t2); });            barrier_raw();
    PH(0, 1, 1, [&] { stB(0, 0, t2); }); VMCNT(8);  barrier_raw();
    PH(1, 0, 0, [&] { stA(0, 1, t2); });            barrier_raw();
    PH(1, 0, 1, [&] { stB(0, 1, t2); }); VMCNT(8);  barrier_raw();
    PH(1, 1, 0, [&] { stA(1, 0, t3); });            barrier_raw();
    PH(1, 1, 1, [&] { stB(1, 0, t3); }); VMCNT(8);  barrier_raw();
  }
  // peel: tiles NT-2 (buf0, certified), NT-1 (buf1). Waits drain 8 -> 4 -> 0.
  PH(0, 0, 0, [&] { stA(1, 1, NT - 1); });           barrier_raw();
  PH(0, 0, 1, [&] { stB(1, 1, NT - 1); }); VMCNT(8); barrier_raw();
  PH(0, 1, 0, NOST);                                 barrier_raw();
  PH(0, 1, 1, NOST);                       VMCNT(4); barrier_raw();
  PH(1, 0, 0, NOST);                                 barrier_raw();
  PH(1, 0, 1, NOST);                       VMCNT(0); barrier_raw();
  PH(1, 1, 0, NOST);                                 barrier_raw();
  PH(1, 1, 1, NOST);

  const int crow0 = bm * 256 + wr * 128;
  const int ccol0 = bn * 256 + wn * 64;
#pragma unroll
  for (int f = 0; f < 8; ++f)
#pragma unroll
    for (int g = 0; g < 4; ++g)
#pragma unroll
      for (int j = 0; j < 4; ++j)
        C[(size_t)(crow0 + f * 16 + lg * 4 + j) * N + ccol0 + g * 16 + lr] =
            f2bf(acc[f][g][j]);
}

// ================= GEMM2: out = ctxb @ WobT^T + bias =================
// M=4096 K=8192 N=2048. BM=256, BN=128, BK=64; 8 waves (4M x 2N); 4 phases/iter.
// Invariant: 9 loads outstanding at each VMCNT(6) -> completes the 3-load region
// read next phase; vmcnt always followed by barrier before reads. Tail: 6->3->0.
__global__ __launch_bounds__(512) void gemm2_4ph(const u16* __restrict__ A,
                                                 const u16* __restrict__ Bt,
                                                 float* __restrict__ Cf,
                                                 const float* __restrict__ bias) {
  constexpr int K = 8192, N = 2048, NT = 128;
  __shared__ __align__(16) u16 lA[2][2][8192];   // 64KB
  __shared__ __align__(16) u16 lB[2][2][4096];   // 32KB
  const int t = threadIdx.x, w = t >> 6, l = t & 63;
  const int lr = l & 15, lg = l >> 4;
  const int wr = w >> 1, wn = w & 1;
  const int swz = (blockIdx.x & 7) * 32 + (blockIdx.x >> 3);  // 256 blocks
  const int bm = swz & 15, bn = swz >> 4;                      // 16 x 16

  const size_t aBase = (size_t)(bm * 256) * K;
  const size_t bBase = (size_t)(bn * 128) * K;
  const int lslog = (t & 3) ^ ((t >> 3) & 3);
  const int r128 = t >> 2;
  const int aswz = (lg ^ ((lr >> 1) & 3)) << 4;

  auto stA = [&](int buf, int kk, int tile) {
#pragma unroll
    for (int i = 0; i < 2; ++i) {
      int row = i * 128 + r128;
      glds16(A + aBase + (size_t)row * K + tile * 64 + kk * 32 + lslog * 8,
             &lA[buf][kk][i * 4096 + t * 8]);
    }
  };
  auto stB = [&](int buf, int kk, int tile) {
    glds16(Bt + bBase + (size_t)r128 * K + tile * 64 + kk * 32 + lslog * 8,
           &lB[buf][kk][t * 8]);
  };

  f32x4 acc[4][4];
#pragma unroll
  for (int f = 0; f < 4; ++f)
#pragma unroll
    for (int g = 0; g < 4; ++g) acc[f][g] = f32x4{0.f, 0.f, 0.f, 0.f};

  // prologue: 9 loads; vmcnt(6) completes (0,0,t0); barrier certifies.
  stA(0, 0, 0); stB(0, 0, 0); stA(0, 1, 0); stB(0, 1, 0); stA(1, 0, 1); stB(1, 0, 1);
  VMCNT(6);
  barrier_raw();

  auto PH = [&](int buf, int kk, auto&& st) {
    bf16x8 af[4], bb[4];
    const char* pA = (const char*)lA[buf][kk];
    const char* pB = (const char*)lB[buf][kk];
#pragma unroll
    for (int f = 0; f < 4; ++f) {
      af[f] = *(const bf16x8*)(pA + (wr * 64 + f * 16 + lr) * 64 + aswz);
      bb[f] = *(const bf16x8*)(pB + (wn * 64 + f * 16 + lr) * 64 + aswz);
    }
    st();
    __builtin_amdgcn_s_setprio(1);
#pragma unroll
    for (int f = 0; f < 4; ++f)
#pragma unroll
      for (int g = 0; g < 4; ++g)
        acc[f][g] = MFMA(af[f], bb[g], acc[f][g]);
    __builtin_amdgcn_s_setprio(0);
  };
  auto NOST = [] {};

  for (int i = 0; i < NT / 2 - 1; ++i) {
    const int t1 = 2 * i + 1, t2 = 2 * i + 2, t3 = 2 * i + 3;
    PH(0, 0, [&] { stA(1, 1, t1); stB(1, 1, t1); }); VMCNT(6); barrier_raw();
    PH(0, 1, [&] { stA(0, 0, t2); stB(0, 0, t2); }); VMCNT(6); barrier_raw();
    PH(1, 0, [&] { stA(0, 1, t2); stB(0, 1, t2); }); VMCNT(6); barrier_raw();
    PH(1, 1, [&] { stA(1, 0, t3); stB(1, 0, t3); }); VMCNT(6); barrier_raw();
  }
  // peel: tiles NT-2 (buf0, certified), NT-1 (buf1). Waits 6 -> 3 -> 0.
  PH(0, 0, [&] { stA(1, 1, NT - 1); stB(1, 1, NT - 1); }); VMCNT(6); barrier_raw();
  PH(0, 1, NOST);                                          VMCNT(3); barrier_raw();
  PH(1, 0, NOST);                                          VMCNT(0); barrier_raw();
  PH(1, 1, NOST);

  const int crow0 = bm * 256 + wr * 64;
  const int ccol0 = bn * 128 + wn * 64;
#pragma unroll
  for (int g = 0; g < 4; ++g) {
    float bv = bias[ccol0 + g * 16 + lr];
#pragma unroll
    for (int f = 0; f < 4; ++f)
#pragma unroll
      for (int j = 0; j < 4; ++j)
        Cf[(size_t)(crow0 + f * 16 + lg * 4 + j) * N + ccol0 + g * 16 + lr] =
            acc[f][g][j] + bv;
  }
}

// ---------------- RoPE in-place; q heads pre-scaled by log2(e)/sqrt(dk) ----
__global__ void rope_kernel(u16* __restrict__ qkv, const float* __restrict__ sinT,
                            const float* __restrict__ cosT) {
  int idx = blockIdx.x * 256 + threadIdx.x;   // 4096 rows * 20 heads * 64
  int d = idx & 63;
  int rh = idx >> 6;
  int head = rh % 20;
  int row = rh / 20;
  int lpos = row & 2047;
  int col = head < 16 ? head * 128 : 2048 + (head - 16) * 128;
  // fold 1/sqrt(128) * log2(e) into Q -> softmax runs in exp2 domain
  float sc = head < 16 ? 0.12751743561938476f : 1.0f;
  u16* p = qkv + (size_t)row * 4608 + col;
  float x1 = bf2f(p[d]), x2 = bf2f(p[d + 64]);
  float c = cosT[lpos * 64 + d], s = sinT[lpos * 64 + d];
  p[d]      = f2bf((x1 * c - x2 * s) * sc);
  p[d + 64] = f2bf((x2 * c + x1 * s) * sc);
}

// ---------------- V^T builder with k-permutation ----------------
// vTp[(b*4+kv)*512 + e][g*32 + pi(k)] = V[g*32+k][e],
// pi(k) = ((k>>2)&3)*8 + ((k>>4)&1)*4 + (k&3)
__global__ void vt_kernel(const u16* __restrict__ qkv, u16* __restrict__ vT) {
  __shared__ u16 tile[32][33];
  int bkv = blockIdx.z;
  int b = bkv >> 2, kv = bkv & 3;
  int e0 = blockIdx.x * 32, l0 = blockIdx.y * 32;
  const u16* src = qkv + (size_t)(b * 2048) * 4608 + 2560 + kv * 512;
  int tx = threadIdx.x, ty = threadIdx.y;   // 32 x 8
  for (int i = 0; i < 32; i += 8)
    tile[ty + i][tx] = src[(size_t)(l0 + ty + i) * 4608 + e0 + tx];
  __syncthreads();
  u16* dst = vT + (size_t)(bkv * 512) * 2048;
  int pi = ((tx >> 2) & 3) * 8 + ((tx >> 4) & 1) * 4 + (tx & 3);
  for (int i = 0; i < 32; i += 8)
    dst[(size_t)(e0 + ty + i) * 2048 + l0 + pi] = tile[tx][ty + i];
}

// ---------------- flash attention v4 (unchanged; R4-validated) ----------------
__global__ __launch_bounds__(512, 2) void attn_kernel(
    const u16* __restrict__ qkv, const u16* __restrict__ vT,
    u16* __restrict__ ctxb) {
  const int wg = blockIdx.x;
  const int pg = wg & 7, qt = wg >> 3;
  const int kvg = pg & 3, b = pg >> 2;
  const int t = threadIdx.x, w = t >> 6, l = t & 63;
  const int lr = l & 15, lg = l >> 4;
  const int h4 = w >> 1, eh = w & 1;
  const int h = kvg * 4 + h4;

  __shared__ __align__(16) u16 lK[2][32 * 128];   // 2 x 8KB
  __shared__ __align__(16) u16 lV[2][256 * 64];   // 2 x 32KB, rows of 128B

  f32x4 zero = {0.f, 0.f, 0.f, 0.f};

  bf16x8 qf[2][4];
  const size_t qbase = (size_t)(b * 2048 + qt * 32);
#pragma unroll
  for (int m = 0; m < 2; ++m)
#pragma unroll
    for (int dc = 0; dc < 4; ++dc)
      qf[m][dc] = *(const bf16x8*)(qkv + (qbase + m * 16 + lr) * 4608 + h * 128 + dc * 32 + lg * 8);

  f32x4 acc[2][16];
#pragma unroll
  for (int m = 0; m < 2; ++m)
#pragma unroll
    for (int e = 0; e < 16; ++e) acc[m][e] = zero;
  float m_r[2] = {-1e30f, -1e30f};
  float l_r[2] = {0.f, 0.f};

  const size_t kbase = (size_t)(b * 2048) * 4608 + 2048 + kvg * 128;
  const size_t vbase = (size_t)((b * 4 + kvg) * 512) * 2048;

  const int krow = t >> 4;
  const int kp = t & 15;
  const int ks = (kp & 8) | ((kp ^ (krow & 7)) & 7);
  const u16* ksrc0 = qkv + kbase + (size_t)krow * 4608 + ks * 8;
  const int vs = (t & 7) ^ ((t >> 3) & 7);
  const int ve0 = (t >> 3) * 2 + (vs >> 2);
  const u16* vsrc0 = vT + vbase + (size_t)ve0 * 2048 + (vs & 3) * 8;

  const int vfoff = (eh * 128 + (lr >> 1)) * 128 +
                    (((((lr & 1) << 2) | lg) ^ ((lr >> 1) & 7)) << 4);

  auto stage = [&](int bi, int kv0) {
    glds16(ksrc0 + (size_t)kv0 * 4608, &lK[bi][t * 8]);
#pragma unroll
    for (int i = 0; i < 4; ++i)
      glds16(vsrc0 + kv0 + (size_t)i * 262144, &lV[bi][i * 4096 + t * 8]);
  };

  stage(0, 0);

  for (int it = 0; it < 64; ++it) {
    const int cur = it & 1;
    __syncthreads();
    if (it + 1 < 64) stage(cur ^ 1, 32 * (it + 1));
    const char* lKc = (const char*)lK[cur];
    const char* lVc = (const char*)lV[cur];

    f32x4 sT[2][2];
    sT[0][0] = zero; sT[0][1] = zero; sT[1][0] = zero; sT[1][1] = zero;
#pragma unroll
    for (int dc = 0; dc < 4; ++dc) {
      int slot = dc * 4 + lg;
      int sw = (slot & 8) | ((slot ^ (lr & 7)) & 7);
#pragma unroll
      for (int kt = 0; kt < 2; ++kt) {
        bf16x8 kf = *(const bf16x8*)(lKc + (kt * 16 + lr) * 256 + sw * 16);
        sT[kt][0] = MFMA(kf, qf[0][dc], sT[kt][0]);
        sT[kt][1] = MFMA(kf, qf[1][dc], sT[kt][1]);
      }
    }

    float rmax[2];
#pragma unroll
    for (int m = 0; m < 2; ++m) {
      float a0 = fmaxf(fmaxf(sT[0][m][0], sT[0][m][1]), fmaxf(sT[0][m][2], sT[0][m][3]));
      float a1 = fmaxf(fmaxf(sT[1][m][0], sT[1][m][1]), fmaxf(sT[1][m][2], sT[1][m][3]));
      float r = fmaxf(a0, a1);
      r = fmaxf(r, __shfl_xor(r, 16));
      r = fmaxf(r, __shfl_xor(r, 32));
      rmax[m] = r;
    }
    bool need = (rmax[0] > m_r[0] + 11.5f) || (rmax[1] > m_r[1] + 11.5f);
    if (__any(need)) {
#pragma unroll
      for (int m = 0; m < 2; ++m) {
        float mn = fmaxf(m_r[m], rmax[m]);
        float al = ex2(m_r[m] - mn);
        m_r[m] = mn; l_r[m] *= al;
        float alj[4];
#pragma unroll
        for (int j = 0; j < 4; ++j) alj[j] = __shfl(al, lg * 4 + j);
#pragma unroll
        for (int e = 0; e < 16; ++e)
#pragma unroll
          for (int j = 0; j < 4; ++j) acc[m][e][j] *= alj[j];
      }
    }

    bf16x8 pf[2];
#pragma unroll
    for (int m = 0; m < 2; ++m) {
      float p0 = ex2(sT[0][m][0] - m_r[m]), p1 = ex2(sT[0][m][1] - m_r[m]);
      float p2 = ex2(sT[0][m][2] - m_r[m]), p3 = ex2(sT[0][m][3] - m_r[m]);
      float p4 = ex2(sT[1][m][0] - m_r[m]), p5 = ex2(sT[1][m][1] - m_r[m]);
      float p6 = ex2(sT[1][m][2] - m_r[m]), p7 = ex2(sT[1][m][3] - m_r[m]);
      float s = ((p0 + p1) + (p2 + p3)) + ((p4 + p5) + (p6 + p7));
      s += __shfl_xor(s, 16);
      s += __shfl_xor(s, 32);
      l_r[m] += s;
      union { bf16x8 v; unsigned wd[4]; } u;
      u.wd[0] = cvt_pk_bf16(p0, p1);
      u.wd[1] = cvt_pk_bf16(p2, p3);
      u.wd[2] = cvt_pk_bf16(p4, p5);
      u.wd[3] = cvt_pk_bf16(p6, p7);
      pf[m] = u.v;
    }

#pragma unroll
    for (int e = 0; e < 16; ++e) {
      bf16x8 vf = *(const bf16x8*)(lVc + vfoff + e * 1024);
      acc[0][e] = MFMA(pf[0], vf, acc[0][e]);
      acc[1][e] = MFMA(pf[1], vf, acc[1][e]);
    }
  }

#pragma unroll
  for (int m = 0; m < 2; ++m) {
    float linv[4];
#pragma unroll
    for (int j = 0; j < 4; ++j) linv[j] = 1.0f / __shfl(l_r[m], lg * 4 + j);
    const size_t orow0 = qbase + m * 16 + lg * 4;
#pragma unroll
    for (int e = 0; e < 16; ++e)
#pragma unroll
      for (int j = 0; j < 4; ++j)
        ctxb[(orow0 + j) * 8192 + h * 512 + eh * 256 + e * 16 + lr] =
            f2bf(acc[m][e][j] * linv[j]);
  }
}

// ---------------- launch ----------------
extern "C" void kernel_launch(void* const* d_in, const int* in_sizes, int n_in,
                              void* d_out, int out_size, void* d_ws, size_t ws_size,
                              hipStream_t stream) {
  const float* x      = (const float*)d_in[0];
  const float* W_attn = (const float*)d_in[1];
  const float* W_out  = (const float*)d_in[2];
  const float* b_out  = (const float*)d_in[3];
  float* out = (float*)d_out;
  char* ws = (char*)d_ws;

  if (ws_size < 158334976u) return;  // need ~151MB scratch

  float* sinT = (float*)(ws + 0);
  float* cosT = (float*)(ws + 524288);
  u16* xb   = (u16*)(ws + 1048576);    // 16MB   (dead after GEMM1)
  u16* WbT  = (u16*)(ws + 17825792);   // 18MB   (dead after GEMM1)
  u16* qkvb = (u16*)(ws + 36700160);   // 36MB
  u16* vT   = (u16*)(ws + 74448896);   // 16MB
  u16* ctxb = (u16*)(ws + 91226112);   // 64MB
  u16* WobT = (u16*)(ws + 1048576);    // 32MB, reuses xb+WbT region post-GEMM1

  rope_tables<<<512, 256, 0, stream>>>(sinT, cosT);
  cast_f32_bf16<<<8192, 256, 0, stream>>>(x, xb);
  transpose_cast<<<dim3(144, 64), dim3(32, 8), 0, stream>>>(W_attn, WbT, 2048, 4608);
  gemm1_8ph<<<288, 512, 0, stream>>>(xb, WbT, qkvb);
  rope_kernel<<<20480, 256, 0, stream>>>(qkvb, sinT, cosT);
  vt_kernel<<<dim3(16, 64, 8), dim3(32, 8), 0, stream>>>(qkvb, vT);
  attn_kernel<<<512, 512, 0, stream>>>(qkvb, vT, ctxb);
  transpose_cast<<<dim3(64, 256), dim3(32, 8), 0, stream>>>(W_out, WobT, 8192, 2048);
  gemm2_4ph<<<256, 512, 0, stream>>>(ctxb, WobT, out, b_out);
}